// Round 12
// baseline (912.497 us; speedup 1.0000x reference)
//
#include <hip/hip_runtime.h>
#include <stdint.h>
#include <stddef.h>

#define BB 64
#define LL 196
#define FF 2048
#define HH 512
#define VV 9488
#define NPAD 9600        // lWb padded rows; pad rows stay finite poison, never stored
#define TT 16
#define KXX 3072         // H + F + H (x' = [xt, att_res, h])
#define MM (BB * LL)     // 12544

typedef short short8 __attribute__((ext_vector_type(8)));
typedef float f32x4 __attribute__((ext_vector_type(4)));
typedef unsigned short u16;
typedef unsigned char u8;

typedef __attribute__((address_space(3))) uint32_t lds_u32_t;
typedef __attribute__((address_space(1))) const uint32_t glb_u32_t;

__device__ __forceinline__ u16 f2bf(float f) {
  uint32_t u = __builtin_bit_cast(uint32_t, f);
  u += 0x7FFFu + ((u >> 16) & 1u);   // RNE
  return (u16)(u >> 16);
}
__device__ __forceinline__ float bf2f(u16 s) {
  return __builtin_bit_cast(float, ((uint32_t)s) << 16);
}
__device__ __forceinline__ float fast_tanh(float x) {
  return 1.0f - 2.0f / (1.0f + __expf(2.0f * x));
}
__device__ __forceinline__ float fast_sig(float x) {
  return 1.0f / (1.0f + __expf(-x));
}
__device__ __forceinline__ float wred_sum(float v) {
#pragma unroll
  for (int o = 32; o; o >>= 1) v += __shfl_xor(v, o, 64);
  return v;
}
__device__ __forceinline__ float wred_max(float v) {
#pragma unroll
  for (int o = 32; o; o >>= 1) v = fmaxf(v, __shfl_xor(v, o, 64));
  return v;
}
__device__ __forceinline__ f32x4 mfma16(short8 a, short8 b, f32x4 c) {
  return __builtin_amdgcn_mfma_f32_16x16x32_bf16(a, b, c, 0, 0, 0);
}
__device__ __forceinline__ short8 ldbf(const u16* p) {
  return *reinterpret_cast<const short8*>(p);
}
// async global->LDS, 16B per lane; lds addr must be wave-base + lane*16 (linear)
__device__ __forceinline__ void gload16(const u16* g, u16* l) {
  __builtin_amdgcn_global_load_lds((glb_u32_t*)g, (lds_u32_t*)l, 16, 0, 0);
}

// ---------------- one fused setup kernel (32B/thread) ----------------
// regions (blocks of 2048 floats): ctx[0,512) lin[512,1024) h2a[1024,1152)
// logit[1152,3524) fc[3524,3588) attb[3588,16132) wc[16132,19204) xemb[19204,19460)
__global__ __launch_bounds__(256) void k_setup(
    const float* __restrict__ ctx_W, u16* __restrict__ ctxWb,
    const float* __restrict__ lin_W, u16* __restrict__ linWb,
    const float* __restrict__ h2a_W, u16* __restrict__ h2aWb,
    const float* __restrict__ logit_W, u16* __restrict__ lWb,
    const float* __restrict__ fc, u16* __restrict__ fcb,
    const float* __restrict__ attf, u16* __restrict__ attb, u8* __restrict__ att8,
    const float* __restrict__ Wih, const float* __restrict__ Whh, u16* __restrict__ Wc,
    const float* __restrict__ emb, const int* __restrict__ seq, u16* __restrict__ Xemb) {
  int blk = blockIdx.x, t = threadIdx.x;
  float4 v0, v1;
  u16* dst = nullptr;
  size_t idx8 = 0;
  bool isAtt = false;
  if (blk < 16132) {
    const float* s; u16* d; int rel;
    if (blk < 512)       { s = ctx_W;   d = ctxWb; rel = blk; }
    else if (blk < 1024) { s = lin_W;   d = linWb; rel = blk - 512; }
    else if (blk < 1152) { s = h2a_W;   d = h2aWb; rel = blk - 1024; }
    else if (blk < 3524) { s = logit_W; d = lWb;   rel = blk - 1152; }
    else if (blk < 3588) { s = fc;      d = fcb;   rel = blk - 3524; }
    else                 { s = attf;    d = attb;  rel = blk - 3588; isAtt = true; }
    idx8 = ((size_t)rel * 256 + t) * 8;
    v0 = *reinterpret_cast<const float4*>(s + idx8);
    v1 = *reinterpret_cast<const float4*>(s + idx8 + 4);
    dst = d;
  } else if (blk < 19204) {
    idx8 = ((size_t)(blk - 16132) * 256 + t) * 8;
    int n = (int)(idx8 / KXX), k = (int)(idx8 - (size_t)n * KXX);
    const float* p = (k < 2560) ? (Wih + (size_t)n * 2560 + k) : (Whh + (size_t)n * HH + (k - 2560));
    v0 = *reinterpret_cast<const float4*>(p);
    v1 = *reinterpret_cast<const float4*>(p + 4);
    dst = Wc;
  } else {
    idx8 = ((size_t)(blk - 19204) * 256 + t) * 8;
    int tt = (int)(idx8 / (BB * HH));
    int r = (int)(idx8 - (size_t)tt * (BB * HH));
    int b = r / HH, k = r - b * HH;
    int tok = seq[b * 17 + tt];
    v0 = *reinterpret_cast<const float4*>(emb + (size_t)tok * HH + k);
    v1 = *reinterpret_cast<const float4*>(emb + (size_t)tok * HH + k + 4);
    dst = Xemb;
  }
  short8 o;
  o[0] = (short)f2bf(v0.x); o[1] = (short)f2bf(v0.y); o[2] = (short)f2bf(v0.z); o[3] = (short)f2bf(v0.w);
  o[4] = (short)f2bf(v1.x); o[5] = (short)f2bf(v1.y); o[6] = (short)f2bf(v1.z); o[7] = (short)f2bf(v1.w);
  *reinterpret_cast<short8*>(dst + idx8) = o;
  if (isAtt && att8) {
    uint32_t lo = __builtin_amdgcn_cvt_pk_fp8_f32(v0.x, v0.y, 0u, false);
    lo = __builtin_amdgcn_cvt_pk_fp8_f32(v0.z, v0.w, lo, true);
    uint32_t hi = __builtin_amdgcn_cvt_pk_fp8_f32(v1.x, v1.y, 0u, false);
    hi = __builtin_amdgcn_cvt_pk_fp8_f32(v1.z, v1.w, hi, true);
    uint2 pv; pv.x = lo; pv.y = hi;
    *reinterpret_cast<uint2*>(att8 + idx8) = pv;
  }
}

// h0 = c0 = fc @ lin_W^T + lin_b
__global__ __launch_bounds__(256) void k_h0(const u16* __restrict__ fcb, const u16* __restrict__ linWb,
                                            const float* __restrict__ lin_b,
                                            u16* __restrict__ hb, float* __restrict__ c) {
  int lane = threadIdx.x & 63;
  int m0 = (threadIdx.x >> 6) * 16, n0 = blockIdx.x * 16;
  const u16* xr = fcb + (size_t)(m0 + (lane & 15)) * FF + ((lane >> 4) * 8);
  const u16* wr = linWb + (size_t)(n0 + (lane & 15)) * FF + ((lane >> 4) * 8);
  f32x4 acc = {0.f, 0.f, 0.f, 0.f};
#pragma unroll 8
  for (int kk = 0; kk < 64; ++kk)
    acc = mfma16(ldbf(xr + kk * 32), ldbf(wr + kk * 32), acc);
  int col = n0 + (lane & 15);
  float bias = lin_b[col];
#pragma unroll
  for (int j = 0; j < 4; ++j) {
    int row = m0 + (lane >> 4) * 4 + j;
    float v = acc[j] + bias;
    hb[row * HH + col] = f2bf(v);
    c[row * HH + col] = v;
  }
}

// p_att = att_feats @ ctx_W^T + ctx_b. 128x128 tile; XCD remap; gload_lds staging (R11-proven).
__global__ __launch_bounds__(256) void k_patt(const u16* __restrict__ attb,
                                              const u16* __restrict__ ctxWb, const float* __restrict__ ctx_b,
                                              u16* __restrict__ p_att) {
  __shared__ __align__(16) u16 As[128][32];
  __shared__ __align__(16) u16 Bs[128][32];
  int d = blockIdx.x;
  int bid = (d & 7) * 49 + (d >> 3);     // 392 = 8*49, bijective XCD remap
  int mb = bid >> 2, nb = bid & 3;       // 98 x 4
  int m0 = mb * 128, n0 = nb * 128;
  int tid = threadIdx.x;
  int wid = tid >> 6, lane = tid & 63;
  int wr = wid >> 1, wc = wid & 1;
  int ar = lane & 15, ak = (lane >> 4) * 8;
  const u16* ga = attb + (size_t)(m0 + (tid >> 2)) * FF + (tid & 3) * 8;
  const u16* gb = ctxWb + (size_t)(n0 + (tid >> 2)) * FF + (tid & 3) * 8;
  u16* la0 = &As[0][0] + tid * 8;
  u16* la1 = &As[64][0] + tid * 8;
  u16* lb0 = &Bs[0][0] + tid * 8;
  u16* lb1 = &Bs[64][0] + tid * 8;

  f32x4 zero = {0.f, 0.f, 0.f, 0.f};
  f32x4 acc[4][4];
#pragma unroll
  for (int i = 0; i < 4; ++i)
#pragma unroll
    for (int j = 0; j < 4; ++j) acc[i][j] = zero;

  for (int ks = 0; ks < 64; ++ks) {
    int k0 = ks * 32;
    __syncthreads();
    gload16(ga + k0, la0);
    gload16(ga + k0 + (size_t)64 * FF, la1);
    gload16(gb + k0, lb0);
    gload16(gb + k0 + (size_t)64 * FF, lb1);
    __syncthreads();
    short8 af[4], bfr[4];
#pragma unroll
    for (int i = 0; i < 4; ++i)
      af[i] = *reinterpret_cast<const short8*>(&As[wr * 64 + i * 16 + ar][ak]);
#pragma unroll
    for (int j = 0; j < 4; ++j)
      bfr[j] = *reinterpret_cast<const short8*>(&Bs[wc * 64 + j * 16 + ar][ak]);
#pragma unroll
    for (int i = 0; i < 4; ++i)
#pragma unroll
      for (int j = 0; j < 4; ++j)
        acc[i][j] = mfma16(af[i], bfr[j], acc[i][j]);
  }
#pragma unroll
  for (int j = 0; j < 4; ++j) {
    int col = n0 + wc * 64 + j * 16 + ar;
    float bias = ctx_b[col];
#pragma unroll
    for (int i = 0; i < 4; ++i)
#pragma unroll
      for (int q = 0; q < 4; ++q) {
        int row = m0 + wr * 64 + i * 16 + (lane >> 4) * 4 + q;
        p_att[(size_t)row * HH + col] = f2bf(acc[i][j][q] + bias);
      }
  }
}

// ---------------- per-step device bodies ----------------
__device__ __forceinline__ void dev_atth(int nt, const u16* __restrict__ hb, const u16* __restrict__ h2aWb,
                                         const float* __restrict__ h2ab, float* __restrict__ ah) {
  int lane = threadIdx.x & 63;
  int m0 = (threadIdx.x >> 6) * 16, n0 = nt * 16;
  int ak = (lane >> 4) * 8;
  const u16* xr = hb + (size_t)(m0 + (lane & 15)) * HH + ak;
  const u16* wr = h2aWb + (size_t)(n0 + (lane & 15)) * HH + ak;
  f32x4 acc = {0.f, 0.f, 0.f, 0.f};
#pragma unroll
  for (int kk = 0; kk < 16; ++kk)
    acc = mfma16(ldbf(xr + kk * 32), ldbf(wr + kk * 32), acc);
  int col = n0 + (lane & 15);
  float bias = h2ab[col];
#pragma unroll
  for (int j = 0; j < 4; ++j)
    ah[(size_t)(m0 + (lane >> 4) * 4 + j) * HH + col] = acc[j] + bias;
}

__device__ __forceinline__ void dev_e(int bid4, const u16* __restrict__ p_att, const float* __restrict__ ah,
                                      const float* __restrict__ alphaW, const float* __restrict__ alphab,
                                      float* __restrict__ e) {
  int gw = bid4 * 4 + (threadIdx.x >> 6);   // [0, 12544)
  int lane = threadIdx.x & 63;
  int b = gw / LL, l = gw - b * LL;
  short8 pa = ldbf(p_att + (size_t)gw * HH + lane * 8);
  const float4* ap = reinterpret_cast<const float4*>(ah + (size_t)b * HH + lane * 8);
  float4 a0 = ap[0], a1 = ap[1];
  const float4* wp = reinterpret_cast<const float4*>(alphaW + lane * 8);
  float4 w0 = wp[0], w1 = wp[1];
  float s = fast_tanh(bf2f((u16)pa[0]) + a0.x) * w0.x
          + fast_tanh(bf2f((u16)pa[1]) + a0.y) * w0.y
          + fast_tanh(bf2f((u16)pa[2]) + a0.z) * w0.z
          + fast_tanh(bf2f((u16)pa[3]) + a0.w) * w0.w
          + fast_tanh(bf2f((u16)pa[4]) + a1.x) * w1.x
          + fast_tanh(bf2f((u16)pa[5]) + a1.y) * w1.y
          + fast_tanh(bf2f((u16)pa[6]) + a1.z) * w1.z
          + fast_tanh(bf2f((u16)pa[7]) + a1.w) * w1.w;
  s = wred_sum(s);
  if (!lane) e[b * 256 + l] = s + alphab[0];
}

// 2 n-tiles per wave (ILP x2), R11-proven
__device__ __forceinline__ void dev_logits2(int nt2, const u16* __restrict__ hb, const u16* __restrict__ lWb,
                                            const float* __restrict__ lb, float* __restrict__ logits) {
  int lane = threadIdx.x & 63;
  int m0 = (threadIdx.x >> 6) * 16, n0 = nt2 * 32;
  int ak = (lane >> 4) * 8;
  const u16* xr = hb + (size_t)(m0 + (lane & 15)) * HH + ak;
  int wn0 = n0 + (lane & 15);
  const u16* b0 = lWb + (size_t)wn0 * HH + ak;
  const u16* b1 = b0 + (size_t)16 * HH;
  f32x4 acc0 = {0.f, 0.f, 0.f, 0.f};
  f32x4 acc1 = {0.f, 0.f, 0.f, 0.f};
#pragma unroll
  for (int kk = 0; kk < 16; ++kk) {
    short8 a = ldbf(xr + kk * 32);
    acc0 = mfma16(a, ldbf(b0 + kk * 32), acc0);
    acc1 = mfma16(a, ldbf(b1 + kk * 32), acc1);
  }
  int col0 = n0 + (lane & 15);
  int col1 = col0 + 16;
  float bias0 = lb[col0];
  float bias1 = (col1 < VV) ? lb[col1] : 0.f;
#pragma unroll
  for (int j = 0; j < 4; ++j) {
    size_t row = (size_t)(m0 + (lane >> 4) * 4 + j) * VV;
    logits[row + col0] = acc0[j] + bias0;
    if (col1 < VV) logits[row + col1] = acc1[j] + bias1;
  }
}

__device__ __forceinline__ void dev_lsm(float* red, int b, const float* __restrict__ logits,
                                        float* __restrict__ out, int tstep) {
  const float4* row4 = reinterpret_cast<const float4*>(logits + (size_t)b * VV);
  int t = threadIdx.x, wid = t >> 6, lane = t & 63;
  float4 v[10];
  float m = -1e30f;
#pragma unroll
  for (int p = 0; p < 10; ++p) {
    int i4 = p * 256 + t;
    if (i4 < VV / 4) {
      v[p] = row4[i4];
      m = fmaxf(m, fmaxf(fmaxf(v[p].x, v[p].y), fmaxf(v[p].z, v[p].w)));
    } else {
      v[p] = make_float4(-1e30f, -1e30f, -1e30f, -1e30f);
    }
  }
  m = wred_max(m);
  if (!lane) red[wid] = m;
  __syncthreads();
  m = fmaxf(fmaxf(red[0], red[1]), fmaxf(red[2], red[3]));
  float s = 0.f;
#pragma unroll
  for (int p = 0; p < 10; ++p)
    s += __expf(v[p].x - m) + __expf(v[p].y - m) + __expf(v[p].z - m) + __expf(v[p].w - m);
  s = wred_sum(s);
  if (!lane) red[4 + wid] = s;
  __syncthreads();
  s = red[4] + red[5] + red[6] + red[7];
  float lse = m + __logf(s);
  float4* orow = reinterpret_cast<float4*>(out + ((size_t)b * TT + tstep) * VV);
#pragma unroll
  for (int p = 0; p < 10; ++p) {
    int i4 = p * 256 + t;
    if (i4 < VV / 4)
      orow[i4] = make_float4(v[p].x - lse, v[p].y - lse, v[p].z - lse, v[p].w - lse);
  }
}

// ---------------- per-step kernels ----------------
__global__ __launch_bounds__(256) void k_atth(const u16* __restrict__ hb, const u16* __restrict__ h2aWb,
                                              const float* __restrict__ h2ab, float* __restrict__ ah) {
  dev_atth(blockIdx.x, hb, h2aWb, h2ab, ah);
}
__global__ __launch_bounds__(256) void k_e(const u16* __restrict__ p_att, const float* __restrict__ ah,
                                           const float* __restrict__ alphaW, const float* __restrict__ alphab,
                                           float* __restrict__ e) {
  dev_e(blockIdx.x, p_att, ah, alphaW, alphab, e);
}

// attR: softmax (redundant x4, cheap) + weighted sum. 256 blocks x 8 WAVES
// (2 waves/SIMD for latency hiding); FP8 path halves attb traffic.
template<bool FP8>
__global__ __launch_bounds__(512) void k_attR(const float* __restrict__ e, const u16* __restrict__ attb,
                                              const u8* __restrict__ att8, u16* __restrict__ xatt) {
  __shared__ float w_s[200];
  __shared__ float red[16];
  __shared__ float part[8][512];
  int b = blockIdx.x >> 2, fc4 = blockIdx.x & 3;
  int t = threadIdx.x, wid = t >> 6, lane = t & 63;
  float ev = (t < LL) ? e[b * 256 + t] : -1e30f;
  float m = wred_max(ev);
  if (!lane) red[wid] = m;
  __syncthreads();
  m = fmaxf(fmaxf(fmaxf(red[0], red[1]), fmaxf(red[2], red[3])),
            fmaxf(fmaxf(red[4], red[5]), fmaxf(red[6], red[7])));
  float ex = __expf(ev - m);
  float s = wred_sum(ex);
  if (!lane) red[8 + wid] = s;
  __syncthreads();
  s = ((red[8] + red[9]) + (red[10] + red[11])) + ((red[12] + red[13]) + (red[14] + red[15]));
  if (t < LL) w_s[t] = ex / s;
  __syncthreads();

  int f0 = fc4 * 512 + lane * 8;
  float a8[8] = {0, 0, 0, 0, 0, 0, 0, 0};
  int l0 = wid * 25;
  int lend = (l0 + 25 < LL) ? l0 + 25 : LL;
  if (FP8) {
    const u8* ap = att8 + ((size_t)(b * LL + l0)) * FF + f0;
    for (int l = l0; l < lend; ++l) {
      float wv = w_s[l];
      uint2 pv = *reinterpret_cast<const uint2*>(ap);
      ap += FF;
      a8[0] += wv * __builtin_amdgcn_cvt_f32_fp8(pv.x, 0);
      a8[1] += wv * __builtin_amdgcn_cvt_f32_fp8(pv.x, 1);
      a8[2] += wv * __builtin_amdgcn_cvt_f32_fp8(pv.x, 2);
      a8[3] += wv * __builtin_amdgcn_cvt_f32_fp8(pv.x, 3);
      a8[4] += wv * __builtin_amdgcn_cvt_f32_fp8(pv.y, 0);
      a8[5] += wv * __builtin_amdgcn_cvt_f32_fp8(pv.y, 1);
      a8[6] += wv * __builtin_amdgcn_cvt_f32_fp8(pv.y, 2);
      a8[7] += wv * __builtin_amdgcn_cvt_f32_fp8(pv.y, 3);
    }
  } else {
    const u16* ap = attb + ((size_t)(b * LL + l0)) * FF + f0;
    for (int l = l0; l < lend; ++l) {
      float wv = w_s[l];
      short8 av = ldbf(ap);
      ap += FF;
#pragma unroll
      for (int i = 0; i < 8; ++i) a8[i] += wv * bf2f((u16)av[i]);
    }
  }
  float4* pp = reinterpret_cast<float4*>(&part[wid][lane * 8]);
  pp[0] = make_float4(a8[0], a8[1], a8[2], a8[3]);
  pp[1] = make_float4(a8[4], a8[5], a8[6], a8[7]);
  __syncthreads();
  float v = ((part[0][t] + part[1][t]) + (part[2][t] + part[3][t]))
          + ((part[4][t] + part[5][t]) + (part[6][t] + part[7][t]));
  xatt[(size_t)b * FF + fc4 * 512 + t] = f2bf(v);
}

// gates+LSTM: 128 blocks = jt(32) x mq(4); 4 waves = K-quarters (proven)
__global__ __launch_bounds__(256) void k_gatelstm(const u16* __restrict__ Xemb, const u16* __restrict__ xatt,
                                                  const u16* __restrict__ hb_in, const u16* __restrict__ Wc,
                                                  float* __restrict__ c, u16* __restrict__ hb_out, int tstep) {
  __shared__ float sm[4][4][16][16];
  int jt = blockIdx.x >> 2, mq = blockIdx.x & 3;
  int m0 = mq * 16;
  int lane = threadIdx.x & 63, kq = threadIdx.x >> 6;
  int ar = lane & 15, ak8 = (lane >> 4) * 8;
  int m = m0 + ar;
  int wn = jt * 16 + ar;
  f32x4 zero = {0.f, 0.f, 0.f, 0.f};
  f32x4 acc[4] = {zero, zero, zero, zero};
  const u16* xr0 = Xemb + ((size_t)tstep * BB + m) * HH;
  const u16* xr1 = xatt + (size_t)m * FF;
  const u16* xr2 = hb_in + (size_t)m * HH;

#pragma unroll 4
  for (int kk = 0; kk < 24; ++kk) {
    int k = kq * 768 + kk * 32 + ak8;
    short8 a;
    if (k < 512)       a = ldbf(xr0 + k);
    else if (k < 2560) a = ldbf(xr1 + (k - 512));
    else               a = ldbf(xr2 + (k - 2560));
    short8 bv[4];
#pragma unroll
    for (int g = 0; g < 4; ++g)
      bv[g] = ldbf(Wc + (size_t)(g * 512 + wn) * KXX + k);
#pragma unroll
    for (int g = 0; g < 4; ++g) acc[g] = mfma16(a, bv[g], acc[g]);
  }
#pragma unroll
  for (int g = 0; g < 4; ++g)
#pragma unroll
    for (int q = 0; q < 4; ++q)
      sm[kq][g][(lane >> 4) * 4 + q][ar] = acc[g][q];
  __syncthreads();
  int r = threadIdx.x >> 4, cc = threadIdx.x & 15;
  float gi = sm[0][0][r][cc] + sm[1][0][r][cc] + sm[2][0][r][cc] + sm[3][0][r][cc];
  float gf = sm[0][1][r][cc] + sm[1][1][r][cc] + sm[2][1][r][cc] + sm[3][1][r][cc];
  float gg = sm[0][2][r][cc] + sm[1][2][r][cc] + sm[2][2][r][cc] + sm[3][2][r][cc];
  float go = sm[0][3][r][cc] + sm[1][3][r][cc] + sm[2][3][r][cc] + sm[3][3][r][cc];
  int idx = (m0 + r) * HH + jt * 16 + cc;
  float cn = fast_sig(gf) * c[idx] + fast_sig(gi) * fast_tanh(gg);
  float hn = fast_sig(go) * fast_tanh(cn);
  c[idx] = cn;
  hb_out[idx] = f2bf(hn);
}

// logits(t) [0..296] (2 tiles/wave) + atth(t+1) rider [297..328]
__global__ __launch_bounds__(256) void k_logatt(const u16* __restrict__ hb, const u16* __restrict__ lWb,
                                                const float* __restrict__ lb, float* __restrict__ logits,
                                                const u16* __restrict__ h2aWb, const float* __restrict__ h2ab,
                                                float* __restrict__ ah, int do_next) {
  int bid = blockIdx.x;
  if (bid < 297) dev_logits2(bid, hb, lWb, lb, logits);
  else if (do_next) dev_atth(bid - 297, hb, h2aWb, h2ab, ah);
}
// lsm(t) [0..63] + e(t+1) rider [64..3199]
__global__ __launch_bounds__(256) void k_lsme(const float* __restrict__ logits, float* __restrict__ out,
                                              int tstep, const u16* __restrict__ p_att,
                                              const float* __restrict__ ah, const float* __restrict__ alphaW,
                                              const float* __restrict__ alphab, float* __restrict__ e,
                                              int do_next) {
  __shared__ float red[8];
  int bid = blockIdx.x;
  if (bid < 64) dev_lsm(red, bid, logits, out, tstep);
  else if (do_next) dev_e(bid - 64, p_att, ah, alphaW, alphab, e);
}

// ---------------- host ----------------
extern "C" void kernel_launch(void* const* d_in, const int* in_sizes, int n_in,
                              void* d_out, int out_size, void* d_ws, size_t ws_size,
                              hipStream_t stream) {
  const float* fc      = (const float*)d_in[0];
  const float* attf    = (const float*)d_in[1];
  const int*   seq     = (const int*)d_in[2];
  const float* lin_W   = (const float*)d_in[3];
  const float* lin_b   = (const float*)d_in[4];
  const float* emb     = (const float*)d_in[5];
  const float* Wih     = (const float*)d_in[6];
  const float* Whh     = (const float*)d_in[7];
  const float* ctx_W   = (const float*)d_in[8];
  const float* ctx_b   = (const float*)d_in[9];
  const float* h2a_W   = (const float*)d_in[10];
  const float* h2a_b   = (const float*)d_in[11];
  const float* alpha_W = (const float*)d_in[12];
  const float* alpha_b = (const float*)d_in[13];
  const float* logit_W = (const float*)d_in[14];
  const float* logit_b = (const float*)d_in[15];
  float* out = (float*)d_out;

  char* base = (char*)d_ws;
  size_t off = 0;
  auto alloc = [&](size_t bytes) -> char* {
    off = (off + 255) & ~(size_t)255;
    char* p = base + off;
    off += bytes;
    return p;
  };
  // base footprint ~91.6 MiB (proven to fit); att8 +25.7 MiB guarded by ws_size
  u16*   p_att  = (u16*)alloc((size_t)MM * HH * 2);
  u16*   ctxWb  = (u16*)alloc((size_t)HH * FF * 2);
  u16*   linWb  = (u16*)alloc((size_t)HH * FF * 2);
  u16*   fcb    = (u16*)alloc((size_t)BB * FF * 2);
  u16*   h2aWb  = (u16*)alloc((size_t)HH * HH * 2);
  u16*   Xemb   = (u16*)alloc((size_t)TT * BB * HH * 2);
  float* c      = (float*)alloc((size_t)BB * HH * 4);
  u16*   hbA    = (u16*)alloc((size_t)BB * HH * 2);
  u16*   hbB    = (u16*)alloc((size_t)BB * HH * 2);
  u16*   xatt   = (u16*)alloc((size_t)BB * FF * 2);
  float* eb     = (float*)alloc((size_t)BB * 256 * 4);
  float* ah     = (float*)alloc((size_t)BB * HH * 4);
  float* logits = (float*)alloc((size_t)BB * VV * 4);
  u16*   Wc     = (u16*)alloc((size_t)2048 * KXX * 2);
  u16*   lWb    = (u16*)alloc((size_t)NPAD * HH * 2);
  u16*   attb   = (u16*)alloc((size_t)MM * FF * 2);
  bool useF8 = (((off + 255) & ~(size_t)255) + (size_t)MM * FF) <= ws_size;
  u8* att8 = useF8 ? (u8*)alloc((size_t)MM * FF) : nullptr;

  k_setup<<<19460, 256, 0, stream>>>(ctx_W, ctxWb, lin_W, linWb, h2a_W, h2aWb, logit_W, lWb,
                                     fc, fcb, attf, attb, att8, Wih, Whh, Wc, emb, seq, Xemb);
  k_h0<<<32, 256, 0, stream>>>(fcb, linWb, lin_b, hbA, c);
  k_patt<<<392, 256, 0, stream>>>(attb, ctxWb, ctx_b, p_att);

  // prologue: ah(0), e(0)
  k_atth<<<32, 256, 0, stream>>>(hbA, h2aWb, h2a_b, ah);
  k_e<<<MM / 4, 256, 0, stream>>>(p_att, ah, alpha_W, alpha_b, eb);

  for (int t = 0; t < TT; ++t) {
    u16* hb_in  = (t & 1) ? hbB : hbA;
    u16* hb_out = (t & 1) ? hbA : hbB;
    int more = (t < TT - 1) ? 1 : 0;
    if (useF8) k_attR<true><<<256, 512, 0, stream>>>(eb, attb, att8, xatt);
    else       k_attR<false><<<256, 512, 0, stream>>>(eb, attb, att8, xatt);
    k_gatelstm<<<128, 256, 0, stream>>>(Xemb, xatt, hb_in, Wc, c, hb_out, t);
    k_logatt<<<329, 256, 0, stream>>>(hb_out, lWb, logit_b, logits, h2aWb, h2a_b, ah, more);
    k_lsme<<<64 + MM / 4, 256, 0, stream>>>(logits, out, t, p_att, ah, alpha_W, alpha_b, eb, more);
  }
}

// Round 13
// 789.508 us; speedup vs baseline: 1.1558x; 1.1558x over previous
//
#include <hip/hip_runtime.h>
#include <stdint.h>
#include <stddef.h>

#define BB 64
#define LL 196
#define FF 2048
#define HH 512
#define VV 9488
#define NPAD 9600        // lWb padded rows; pad rows stay finite poison, never stored
#define TT 16
#define KXX 3072         // H + F + H (x' = [xt, att_res, h])
#define MM (BB * LL)     // 12544

typedef short short8 __attribute__((ext_vector_type(8)));
typedef float f32x4 __attribute__((ext_vector_type(4)));
typedef unsigned short u16;

typedef __attribute__((address_space(3))) uint32_t lds_u32_t;
typedef __attribute__((address_space(1))) const uint32_t glb_u32_t;

__device__ __forceinline__ u16 f2bf(float f) {
  uint32_t u = __builtin_bit_cast(uint32_t, f);
  u += 0x7FFFu + ((u >> 16) & 1u);   // RNE
  return (u16)(u >> 16);
}
__device__ __forceinline__ float bf2f(u16 s) {
  return __builtin_bit_cast(float, ((uint32_t)s) << 16);
}
__device__ __forceinline__ float fast_tanh(float x) {
  return 1.0f - 2.0f / (1.0f + __expf(2.0f * x));
}
__device__ __forceinline__ float fast_sig(float x) {
  return 1.0f / (1.0f + __expf(-x));
}
__device__ __forceinline__ float wred_sum(float v) {
#pragma unroll
  for (int o = 32; o; o >>= 1) v += __shfl_xor(v, o, 64);
  return v;
}
__device__ __forceinline__ float wred_max(float v) {
#pragma unroll
  for (int o = 32; o; o >>= 1) v = fmaxf(v, __shfl_xor(v, o, 64));
  return v;
}
__device__ __forceinline__ f32x4 mfma16(short8 a, short8 b, f32x4 c) {
  return __builtin_amdgcn_mfma_f32_16x16x32_bf16(a, b, c, 0, 0, 0);
}
__device__ __forceinline__ short8 ldbf(const u16* p) {
  return *reinterpret_cast<const short8*>(p);
}
// async global->LDS, 16B per lane; lds addr must be wave-base + lane*16 (linear)
__device__ __forceinline__ void gload16(const u16* g, u16* l) {
  __builtin_amdgcn_global_load_lds((glb_u32_t*)g, (lds_u32_t*)l, 16, 0, 0);
}

// ---------------- one fused setup kernel (R11-proven, 67us) ----------------
// regions: ctx[0,1024) lin[1024,2048) h2a[2048,2304) logit[2304,7048)
// fc[7048,7176) attb[7176,32264) wc[32264,38408) xemb[38408,38920)
__global__ __launch_bounds__(256) void k_setup(
    const float* __restrict__ ctx_W, u16* __restrict__ ctxWb,
    const float* __restrict__ lin_W, u16* __restrict__ linWb,
    const float* __restrict__ h2a_W, u16* __restrict__ h2aWb,
    const float* __restrict__ logit_W, u16* __restrict__ lWb,
    const float* __restrict__ fc, u16* __restrict__ fcb,
    const float* __restrict__ attf, u16* __restrict__ attb,
    const float* __restrict__ Wih, const float* __restrict__ Whh, u16* __restrict__ Wc,
    const float* __restrict__ emb, const int* __restrict__ seq, u16* __restrict__ Xemb) {
  int blk = blockIdx.x, t = threadIdx.x;
  if (blk < 32264) {
    const float* s; u16* d; int rel;
    if (blk < 1024)      { s = ctx_W;   d = ctxWb; rel = blk; }
    else if (blk < 2048) { s = lin_W;   d = linWb; rel = blk - 1024; }
    else if (blk < 2304) { s = h2a_W;   d = h2aWb; rel = blk - 2048; }
    else if (blk < 7048) { s = logit_W; d = lWb;   rel = blk - 2304; }
    else if (blk < 7176) { s = fc;      d = fcb;   rel = blk - 7048; }
    else                 { s = attf;    d = attb;  rel = blk - 7176; }
    int i = rel * 256 + t;
    float4 v = reinterpret_cast<const float4*>(s)[i];
    ushort4 o; o.x = f2bf(v.x); o.y = f2bf(v.y); o.z = f2bf(v.z); o.w = f2bf(v.w);
    reinterpret_cast<ushort4*>(d)[i] = o;
  } else if (blk < 38408) {
    int i = (blk - 32264) * 256 + t;
    int idx = i * 4;
    int n = idx / KXX, k = idx - n * KXX;
    const float* p = (k < 2560) ? (Wih + (size_t)n * 2560 + k) : (Whh + (size_t)n * HH + (k - 2560));
    float4 v = *reinterpret_cast<const float4*>(p);
    ushort4 o; o.x = f2bf(v.x); o.y = f2bf(v.y); o.z = f2bf(v.z); o.w = f2bf(v.w);
    reinterpret_cast<ushort4*>(Wc)[i] = o;
  } else {
    int i = (blk - 38408) * 256 + t;
    int idx = i * 4;
    int tt = idx / (BB * HH);
    int r = idx - tt * (BB * HH);
    int b = r / HH, k = r - b * HH;
    int tok = seq[b * 17 + tt];
    float4 v = *reinterpret_cast<const float4*>(emb + (size_t)tok * HH + k);
    ushort4 o; o.x = f2bf(v.x); o.y = f2bf(v.y); o.z = f2bf(v.z); o.w = f2bf(v.w);
    reinterpret_cast<ushort4*>(Xemb)[i] = o;
  }
}

// h0 = c0 = fc @ lin_W^T + lin_b  -> Xh slice 0 (bf16) and c (f32)
__global__ __launch_bounds__(256) void k_h0(const u16* __restrict__ fcb, const u16* __restrict__ linWb,
                                            const float* __restrict__ lin_b,
                                            u16* __restrict__ hb, float* __restrict__ c) {
  int lane = threadIdx.x & 63;
  int m0 = (threadIdx.x >> 6) * 16, n0 = blockIdx.x * 16;
  const u16* xr = fcb + (size_t)(m0 + (lane & 15)) * FF + ((lane >> 4) * 8);
  const u16* wr = linWb + (size_t)(n0 + (lane & 15)) * FF + ((lane >> 4) * 8);
  f32x4 acc = {0.f, 0.f, 0.f, 0.f};
#pragma unroll 8
  for (int kk = 0; kk < 64; ++kk)
    acc = mfma16(ldbf(xr + kk * 32), ldbf(wr + kk * 32), acc);
  int col = n0 + (lane & 15);
  float bias = lin_b[col];
#pragma unroll
  for (int j = 0; j < 4; ++j) {
    int row = m0 + (lane >> 4) * 4 + j;
    float v = acc[j] + bias;
    hb[row * HH + col] = f2bf(v);
    c[row * HH + col] = v;
  }
}

// p_att = att_feats @ ctx_W^T + ctx_b. 128x128 tile; XCD remap; gload_lds staging (R11-proven).
__global__ __launch_bounds__(256) void k_patt(const u16* __restrict__ attb,
                                              const u16* __restrict__ ctxWb, const float* __restrict__ ctx_b,
                                              u16* __restrict__ p_att) {
  __shared__ __align__(16) u16 As[128][32];
  __shared__ __align__(16) u16 Bs[128][32];
  int d = blockIdx.x;
  int bid = (d & 7) * 49 + (d >> 3);     // 392 = 8*49, bijective XCD remap
  int mb = bid >> 2, nb = bid & 3;       // 98 x 4
  int m0 = mb * 128, n0 = nb * 128;
  int tid = threadIdx.x;
  int wid = tid >> 6, lane = tid & 63;
  int wr = wid >> 1, wc = wid & 1;
  int ar = lane & 15, ak = (lane >> 4) * 8;
  const u16* ga = attb + (size_t)(m0 + (tid >> 2)) * FF + (tid & 3) * 8;
  const u16* gb = ctxWb + (size_t)(n0 + (tid >> 2)) * FF + (tid & 3) * 8;
  u16* la0 = &As[0][0] + tid * 8;
  u16* la1 = &As[64][0] + tid * 8;
  u16* lb0 = &Bs[0][0] + tid * 8;
  u16* lb1 = &Bs[64][0] + tid * 8;

  f32x4 zero = {0.f, 0.f, 0.f, 0.f};
  f32x4 acc[4][4];
#pragma unroll
  for (int i = 0; i < 4; ++i)
#pragma unroll
    for (int j = 0; j < 4; ++j) acc[i][j] = zero;

  for (int ks = 0; ks < 64; ++ks) {
    int k0 = ks * 32;
    __syncthreads();
    gload16(ga + k0, la0);
    gload16(ga + k0 + (size_t)64 * FF, la1);
    gload16(gb + k0, lb0);
    gload16(gb + k0 + (size_t)64 * FF, lb1);
    __syncthreads();
    short8 af[4], bfr[4];
#pragma unroll
    for (int i = 0; i < 4; ++i)
      af[i] = *reinterpret_cast<const short8*>(&As[wr * 64 + i * 16 + ar][ak]);
#pragma unroll
    for (int j = 0; j < 4; ++j)
      bfr[j] = *reinterpret_cast<const short8*>(&Bs[wc * 64 + j * 16 + ar][ak]);
#pragma unroll
    for (int i = 0; i < 4; ++i)
#pragma unroll
      for (int j = 0; j < 4; ++j)
        acc[i][j] = mfma16(af[i], bfr[j], acc[i][j]);
  }
#pragma unroll
  for (int j = 0; j < 4; ++j) {
    int col = n0 + wc * 64 + j * 16 + ar;
    float bias = ctx_b[col];
#pragma unroll
    for (int i = 0; i < 4; ++i)
#pragma unroll
      for (int q = 0; q < 4; ++q) {
        int row = m0 + wr * 64 + i * 16 + (lane >> 4) * 4 + q;
        p_att[(size_t)row * HH + col] = f2bf(acc[i][j][q] + bias);
      }
  }
}

// ---------------- per-step device bodies (R8/R11-proven) ----------------
__device__ __forceinline__ void dev_atth(int nt, const u16* __restrict__ hb, const u16* __restrict__ h2aWb,
                                         const float* __restrict__ h2ab, float* __restrict__ ah) {
  int lane = threadIdx.x & 63;
  int m0 = (threadIdx.x >> 6) * 16, n0 = nt * 16;
  int ak = (lane >> 4) * 8;
  const u16* xr = hb + (size_t)(m0 + (lane & 15)) * HH + ak;
  const u16* wr = h2aWb + (size_t)(n0 + (lane & 15)) * HH + ak;
  f32x4 acc = {0.f, 0.f, 0.f, 0.f};
#pragma unroll
  for (int kk = 0; kk < 16; ++kk)
    acc = mfma16(ldbf(xr + kk * 32), ldbf(wr + kk * 32), acc);
  int col = n0 + (lane & 15);
  float bias = h2ab[col];
#pragma unroll
  for (int j = 0; j < 4; ++j)
    ah[(size_t)(m0 + (lane >> 4) * 4 + j) * HH + col] = acc[j] + bias;
}

__device__ __forceinline__ void dev_e(int bid4, const u16* __restrict__ p_att, const float* __restrict__ ah,
                                      const float* __restrict__ alphaW, const float* __restrict__ alphab,
                                      float* __restrict__ e) {
  int gw = bid4 * 4 + (threadIdx.x >> 6);   // [0, 12544)
  int lane = threadIdx.x & 63;
  int b = gw / LL, l = gw - b * LL;
  short8 pa = ldbf(p_att + (size_t)gw * HH + lane * 8);
  const float4* ap = reinterpret_cast<const float4*>(ah + (size_t)b * HH + lane * 8);
  float4 a0 = ap[0], a1 = ap[1];
  const float4* wp = reinterpret_cast<const float4*>(alphaW + lane * 8);
  float4 w0 = wp[0], w1 = wp[1];
  float s = fast_tanh(bf2f((u16)pa[0]) + a0.x) * w0.x
          + fast_tanh(bf2f((u16)pa[1]) + a0.y) * w0.y
          + fast_tanh(bf2f((u16)pa[2]) + a0.z) * w0.z
          + fast_tanh(bf2f((u16)pa[3]) + a0.w) * w0.w
          + fast_tanh(bf2f((u16)pa[4]) + a1.x) * w1.x
          + fast_tanh(bf2f((u16)pa[5]) + a1.y) * w1.y
          + fast_tanh(bf2f((u16)pa[6]) + a1.z) * w1.z
          + fast_tanh(bf2f((u16)pa[7]) + a1.w) * w1.w;
  s = wred_sum(s);
  if (!lane) e[b * 256 + l] = s + alphab[0];
}

// ---------------- per-step kernels (4 per step, logits deferred) ----------------
__global__ __launch_bounds__(256) void k_atth(const u16* __restrict__ hb, const u16* __restrict__ h2aWb,
                                              const float* __restrict__ h2ab, float* __restrict__ ah) {
  dev_atth(blockIdx.x, hb, h2aWb, h2ab, ah);
}
__global__ __launch_bounds__(256) void k_e(const u16* __restrict__ p_att, const float* __restrict__ ah,
                                           const float* __restrict__ alphaW, const float* __restrict__ alphab,
                                           float* __restrict__ e) {
  dev_e(blockIdx.x, p_att, ah, alphaW, alphab, e);
}

// attR: softmax(e[b,:]) per block (redundant x4, cheap) then weighted sum.
// 256 blocks = b(64) x f-chunk(4) of 512 feats (R8/R11-proven body).
__global__ __launch_bounds__(256) void k_attR(const float* __restrict__ e, const u16* __restrict__ attb,
                                              u16* __restrict__ xatt) {
  __shared__ float w_s[LL];
  __shared__ float red[8];
  __shared__ float part[4][512];
  int b = blockIdx.x >> 2, fc4 = blockIdx.x & 3;
  int t = threadIdx.x, wid = t >> 6, lane = t & 63;
  float ev = (t < LL) ? e[b * 256 + t] : -1e30f;
  float m = wred_max(ev);
  if (!lane) red[wid] = m;
  __syncthreads();
  m = fmaxf(fmaxf(red[0], red[1]), fmaxf(red[2], red[3]));
  float ex = __expf(ev - m);
  float s = wred_sum(ex);
  if (!lane) red[4 + wid] = s;
  __syncthreads();
  s = red[4] + red[5] + red[6] + red[7];
  if (t < LL) w_s[t] = ex / s;
  __syncthreads();

  int f0 = fc4 * 512 + lane * 8;
  float a8[8] = {0, 0, 0, 0, 0, 0, 0, 0};
  int l0 = wid * 49;
  const u16* ap = attb + ((size_t)(b * LL + l0)) * FF + f0;
#pragma unroll 7
  for (int l = 0; l < 49; ++l) {
    float w = w_s[l0 + l];
    short8 av = ldbf(ap);
    ap += FF;
#pragma unroll
    for (int i = 0; i < 8; ++i) a8[i] += w * bf2f((u16)av[i]);
  }
  float4* pp = reinterpret_cast<float4*>(&part[wid][lane * 8]);
  pp[0] = make_float4(a8[0], a8[1], a8[2], a8[3]);
  pp[1] = make_float4(a8[4], a8[5], a8[6], a8[7]);
  __syncthreads();
  int f = 2 * t;
  float v0 = part[0][f] + part[1][f] + part[2][f] + part[3][f];
  float v1 = part[0][f + 1] + part[1][f + 1] + part[2][f + 1] + part[3][f + 1];
  ushort2 o; o.x = f2bf(v0); o.y = f2bf(v1);
  *reinterpret_cast<ushort2*>(xatt + (size_t)b * FF + fc4 * 512 + f) = o;
}

// gates+LSTM: 128 blocks = jt(32) x mq(4); 4 waves = K-quarters (proven)
__global__ __launch_bounds__(256) void k_gatelstm(const u16* __restrict__ Xemb, const u16* __restrict__ xatt,
                                                  const u16* __restrict__ hb_in, const u16* __restrict__ Wc,
                                                  float* __restrict__ c, u16* __restrict__ hb_out, int tstep) {
  __shared__ float sm[4][4][16][16];
  int jt = blockIdx.x >> 2, mq = blockIdx.x & 3;
  int m0 = mq * 16;
  int lane = threadIdx.x & 63, kq = threadIdx.x >> 6;
  int ar = lane & 15, ak8 = (lane >> 4) * 8;
  int m = m0 + ar;
  int wn = jt * 16 + ar;
  f32x4 zero = {0.f, 0.f, 0.f, 0.f};
  f32x4 acc[4] = {zero, zero, zero, zero};
  const u16* xr0 = Xemb + ((size_t)tstep * BB + m) * HH;
  const u16* xr1 = xatt + (size_t)m * FF;
  const u16* xr2 = hb_in + (size_t)m * HH;

#pragma unroll 4
  for (int kk = 0; kk < 24; ++kk) {
    int k = kq * 768 + kk * 32 + ak8;
    short8 a;
    if (k < 512)       a = ldbf(xr0 + k);
    else if (k < 2560) a = ldbf(xr1 + (k - 512));
    else               a = ldbf(xr2 + (k - 2560));
    short8 bv[4];
#pragma unroll
    for (int g = 0; g < 4; ++g)
      bv[g] = ldbf(Wc + (size_t)(g * 512 + wn) * KXX + k);
#pragma unroll
    for (int g = 0; g < 4; ++g) acc[g] = mfma16(a, bv[g], acc[g]);
  }
#pragma unroll
  for (int g = 0; g < 4; ++g)
#pragma unroll
    for (int q = 0; q < 4; ++q)
      sm[kq][g][(lane >> 4) * 4 + q][ar] = acc[g][q];
  __syncthreads();
  int r = threadIdx.x >> 4, cc = threadIdx.x & 15;
  float gi = sm[0][0][r][cc] + sm[1][0][r][cc] + sm[2][0][r][cc] + sm[3][0][r][cc];
  float gf = sm[0][1][r][cc] + sm[1][1][r][cc] + sm[2][1][r][cc] + sm[3][1][r][cc];
  float gg = sm[0][2][r][cc] + sm[1][2][r][cc] + sm[2][2][r][cc] + sm[3][2][r][cc];
  float go = sm[0][3][r][cc] + sm[1][3][r][cc] + sm[2][3][r][cc] + sm[3][3][r][cc];
  int idx = (m0 + r) * HH + jt * 16 + cc;
  float cn = fast_sig(gf) * c[idx] + fast_sig(gi) * fast_tanh(gg);
  float hn = fast_sig(go) * fast_tanh(cn);
  c[idx] = cn;
  hb_out[idx] = f2bf(hn);
}

// ---------------- deferred logits (writes straight into d_out; R10-proven) ----------------
// logits = XhL[1024,512] @ lWb^T + lb.  128x128 tiles, 600 blocks = 8 m x 75 n
// (N padded to 9600; pad rows finite poison; cols >= VV skipped on store).
// A-row r = t*64 + b  ->  out row b*TT + t.
__global__ __launch_bounds__(256) void k_logall(const u16* __restrict__ XhL, const u16* __restrict__ lWb,
                                                const float* __restrict__ lb, float* __restrict__ out) {
  __shared__ __align__(16) u16 As[128][32];
  __shared__ __align__(16) u16 Bs[128][32];
  int d = blockIdx.x;
  int mb = d & 7, nb = d >> 3;          // blocks sharing A-panel stay adjacent
  int m0 = mb * 128, n0 = nb * 128;
  int tid = threadIdx.x;
  int wid = tid >> 6, lane = tid & 63;
  int wr = wid >> 1, wc = wid & 1;
  int ar = lane & 15, ak = (lane >> 4) * 8;
  int rt = tid >> 1, st = tid & 1;
  const u16* agp = XhL + (size_t)(m0 + rt) * HH + st * 16;
  const u16* bgp = lWb + (size_t)(n0 + rt) * HH + st * 16;

  f32x4 zero = {0.f, 0.f, 0.f, 0.f};
  f32x4 acc[4][4];
#pragma unroll
  for (int i = 0; i < 4; ++i)
#pragma unroll
    for (int j = 0; j < 4; ++j) acc[i][j] = zero;

  for (int ks = 0; ks < 16; ++ks) {
    int k0 = ks * 32;
    short8 a0 = ldbf(agp + k0);
    short8 a1 = ldbf(agp + k0 + 8);
    short8 b0 = ldbf(bgp + k0);
    short8 b1 = ldbf(bgp + k0 + 8);
    __syncthreads();
    *reinterpret_cast<short8*>(&As[rt][st * 16]) = a0;
    *reinterpret_cast<short8*>(&As[rt][st * 16 + 8]) = a1;
    *reinterpret_cast<short8*>(&Bs[rt][st * 16]) = b0;
    *reinterpret_cast<short8*>(&Bs[rt][st * 16 + 8]) = b1;
    __syncthreads();
    short8 af[4], bfr[4];
#pragma unroll
    for (int i = 0; i < 4; ++i)
      af[i] = *reinterpret_cast<const short8*>(&As[wr * 64 + i * 16 + ar][ak]);
#pragma unroll
    for (int j = 0; j < 4; ++j)
      bfr[j] = *reinterpret_cast<const short8*>(&Bs[wc * 64 + j * 16 + ar][ak]);
#pragma unroll
    for (int i = 0; i < 4; ++i)
#pragma unroll
      for (int j = 0; j < 4; ++j)
        acc[i][j] = mfma16(af[i], bfr[j], acc[i][j]);
  }
#pragma unroll
  for (int j = 0; j < 4; ++j) {
    int col = n0 + wc * 64 + j * 16 + ar;
    if (col >= VV) continue;
    float bias = lb[col];
#pragma unroll
    for (int i = 0; i < 4; ++i)
#pragma unroll
      for (int q = 0; q < 4; ++q) {
        int row = m0 + wr * 64 + i * 16 + (lane >> 4) * 4 + q;
        int bb = row & 63, ts = row >> 6;
        out[((size_t)(bb * TT + ts)) * VV + col] = acc[i][j][q] + bias;
      }
  }
}

// in-place log-softmax on all 1024 out rows (R10-proven)
__global__ __launch_bounds__(256) void k_lsmall(float* __restrict__ out) {
  __shared__ float red[8];
  float* row = out + (size_t)blockIdx.x * VV;
  float4* row4 = reinterpret_cast<float4*>(row);
  int t = threadIdx.x, wid = t >> 6, lane = t & 63;
  float4 v[10];
  float m = -1e30f;
#pragma unroll
  for (int p = 0; p < 10; ++p) {
    int i4 = p * 256 + t;
    if (i4 < VV / 4) {
      v[p] = row4[i4];
      m = fmaxf(m, fmaxf(fmaxf(v[p].x, v[p].y), fmaxf(v[p].z, v[p].w)));
    } else {
      v[p] = make_float4(-1e30f, -1e30f, -1e30f, -1e30f);
    }
  }
  m = wred_max(m);
  if (!lane) red[wid] = m;
  __syncthreads();
  m = fmaxf(fmaxf(red[0], red[1]), fmaxf(red[2], red[3]));
  float s = 0.f;
#pragma unroll
  for (int p = 0; p < 10; ++p)
    s += __expf(v[p].x - m) + __expf(v[p].y - m) + __expf(v[p].z - m) + __expf(v[p].w - m);
  s = wred_sum(s);
  if (!lane) red[4 + wid] = s;
  __syncthreads();
  s = red[4] + red[5] + red[6] + red[7];
  float lse = m + __logf(s);
#pragma unroll
  for (int p = 0; p < 10; ++p) {
    int i4 = p * 256 + t;
    if (i4 < VV / 4)
      row4[i4] = make_float4(v[p].x - lse, v[p].y - lse, v[p].z - lse, v[p].w - lse);
  }
}

// ---------------- host ----------------
extern "C" void kernel_launch(void* const* d_in, const int* in_sizes, int n_in,
                              void* d_out, int out_size, void* d_ws, size_t ws_size,
                              hipStream_t stream) {
  const float* fc      = (const float*)d_in[0];
  const float* attf    = (const float*)d_in[1];
  const int*   seq     = (const int*)d_in[2];
  const float* lin_W   = (const float*)d_in[3];
  const float* lin_b   = (const float*)d_in[4];
  const float* emb     = (const float*)d_in[5];
  const float* Wih     = (const float*)d_in[6];
  const float* Whh     = (const float*)d_in[7];
  const float* ctx_W   = (const float*)d_in[8];
  const float* ctx_b   = (const float*)d_in[9];
  const float* h2a_W   = (const float*)d_in[10];
  const float* h2a_b   = (const float*)d_in[11];
  const float* alpha_W = (const float*)d_in[12];
  const float* alpha_b = (const float*)d_in[13];
  const float* logit_W = (const float*)d_in[14];
  const float* logit_b = (const float*)d_in[15];
  float* out = (float*)d_out;

  char* base = (char*)d_ws;
  size_t off = 0;
  auto alloc = [&](size_t bytes) -> char* {
    off = (off + 255) & ~(size_t)255;
    char* p = base + off;
    off += bytes;
    return p;
  };
  // footprint ~90.3 MiB (< proven ~91.6)
  u16*   p_att  = (u16*)alloc((size_t)MM * HH * 2);
  u16*   ctxWb  = (u16*)alloc((size_t)HH * FF * 2);
  u16*   linWb  = (u16*)alloc((size_t)HH * FF * 2);
  u16*   fcb    = (u16*)alloc((size_t)BB * FF * 2);
  u16*   h2aWb  = (u16*)alloc((size_t)HH * HH * 2);
  u16*   Xemb   = (u16*)alloc((size_t)TT * BB * HH * 2);
  float* c      = (float*)alloc((size_t)BB * HH * 4);
  u16*   Xh     = (u16*)alloc((size_t)(TT + 1) * BB * HH * 2);   // slice 0 = h0
  u16*   xatt   = (u16*)alloc((size_t)BB * FF * 2);
  float* eb     = (float*)alloc((size_t)BB * 256 * 4);
  float* ah     = (float*)alloc((size_t)BB * HH * 4);
  u16*   Wc     = (u16*)alloc((size_t)2048 * KXX * 2);
  u16*   lWb    = (u16*)alloc((size_t)NPAD * HH * 2);   // pad rows: finite poison, never stored
  u16*   attb   = (u16*)alloc((size_t)MM * FF * 2);
  (void)ws_size;

  k_setup<<<38920, 256, 0, stream>>>(ctx_W, ctxWb, lin_W, linWb, h2a_W, h2aWb, logit_W, lWb,
                                     fc, fcb, attf, attb, Wih, Whh, Wc, emb, seq, Xemb);
  k_h0<<<32, 256, 0, stream>>>(fcb, linWb, lin_b, Xh, c);
  k_patt<<<392, 256, 0, stream>>>(attb, ctxWb, ctx_b, p_att);

  // prologue: ah(0), e(0)
  k_atth<<<32, 256, 0, stream>>>(Xh, h2aWb, h2a_b, ah);
  k_e<<<MM / 4, 256, 0, stream>>>(p_att, ah, alpha_W, alpha_b, eb);

  for (int t = 0; t < TT; ++t) {
    u16* ht  = Xh + (size_t)t * BB * HH;
    u16* htn = Xh + (size_t)(t + 1) * BB * HH;
    k_attR<<<256, 256, 0, stream>>>(eb, attb, xatt);
    k_gatelstm<<<128, 256, 0, stream>>>(Xemb, xatt, ht, Wc, c, htn, t);
    if (t < TT - 1) {
      k_atth<<<32, 256, 0, stream>>>(htn, h2aWb, h2a_b, ah);
      k_e<<<MM / 4, 256, 0, stream>>>(p_att, ah, alpha_W, alpha_b, eb);
    }
  }
  k_logall<<<600, 256, 0, stream>>>(Xh + (size_t)BB * HH, lWb, logit_b, out);
  k_lsmall<<<TT * BB, 256, 0, stream>>>(out);
}

// Round 14
// 788.329 us; speedup vs baseline: 1.1575x; 1.0015x over previous
//
#include <hip/hip_runtime.h>
#include <stdint.h>
#include <stddef.h>

#define BB 64
#define LL 196
#define FF 2048
#define HH 512
#define VV 9488
#define NPAD 9600        // lWb padded rows; pad rows stay finite poison, never stored
#define TT 16
#define KXX 3072         // H + F + H (x' = [xt, att_res, h])
#define MM (BB * LL)     // 12544

typedef short short8 __attribute__((ext_vector_type(8)));
typedef short short4v __attribute__((ext_vector_type(4)));
typedef float f32x4 __attribute__((ext_vector_type(4)));
typedef unsigned short u16;

typedef __attribute__((address_space(3))) uint32_t lds_u32_t;
typedef __attribute__((address_space(1))) const uint32_t glb_u32_t;

__device__ __forceinline__ u16 f2bf(float f) {
  uint32_t u = __builtin_bit_cast(uint32_t, f);
  u += 0x7FFFu + ((u >> 16) & 1u);   // RNE
  return (u16)(u >> 16);
}
__device__ __forceinline__ float bf2f(u16 s) {
  return __builtin_bit_cast(float, ((uint32_t)s) << 16);
}
__device__ __forceinline__ float fast_tanh(float x) {
  return 1.0f - 2.0f / (1.0f + __expf(2.0f * x));
}
__device__ __forceinline__ float fast_sig(float x) {
  return 1.0f / (1.0f + __expf(-x));
}
__device__ __forceinline__ float wred_sum(float v) {
#pragma unroll
  for (int o = 32; o; o >>= 1) v += __shfl_xor(v, o, 64);
  return v;
}
__device__ __forceinline__ float wred_max(float v) {
#pragma unroll
  for (int o = 32; o; o >>= 1) v = fmaxf(v, __shfl_xor(v, o, 64));
  return v;
}
__device__ __forceinline__ f32x4 mfma16(short8 a, short8 b, f32x4 c) {
  return __builtin_amdgcn_mfma_f32_16x16x32_bf16(a, b, c, 0, 0, 0);
}
__device__ __forceinline__ short8 ldbf(const u16* p) {
  return *reinterpret_cast<const short8*>(p);
}
// async global->LDS, 16B per lane; lds addr must be wave-base + lane*16 (linear)
__device__ __forceinline__ void gload16(const u16* g, u16* l) {
  __builtin_amdgcn_global_load_lds((glb_u32_t*)g, (lds_u32_t*)l, 16, 0, 0);
}

// ---------------- one fused setup kernel (R11-proven, ~66us) ----------------
// regions: ctx[0,1024) lin[1024,2048) h2a[2048,2304) logit[2304,7048)
// fc[7048,7176) attb[7176,32264) wc[32264,38408) xemb[38408,38920)
__global__ __launch_bounds__(256) void k_setup(
    const float* __restrict__ ctx_W, u16* __restrict__ ctxWb,
    const float* __restrict__ lin_W, u16* __restrict__ linWb,
    const float* __restrict__ h2a_W, u16* __restrict__ h2aWb,
    const float* __restrict__ logit_W, u16* __restrict__ lWb,
    const float* __restrict__ fc, u16* __restrict__ fcb,
    const float* __restrict__ attf, u16* __restrict__ attb,
    const float* __restrict__ Wih, const float* __restrict__ Whh, u16* __restrict__ Wc,
    const float* __restrict__ emb, const int* __restrict__ seq, u16* __restrict__ Xemb) {
  int blk = blockIdx.x, t = threadIdx.x;
  if (blk < 32264) {
    const float* s; u16* d; int rel;
    if (blk < 1024)      { s = ctx_W;   d = ctxWb; rel = blk; }
    else if (blk < 2048) { s = lin_W;   d = linWb; rel = blk - 1024; }
    else if (blk < 2304) { s = h2a_W;   d = h2aWb; rel = blk - 2048; }
    else if (blk < 7048) { s = logit_W; d = lWb;   rel = blk - 2304; }
    else if (blk < 7176) { s = fc;      d = fcb;   rel = blk - 7048; }
    else                 { s = attf;    d = attb;  rel = blk - 7176; }
    int i = rel * 256 + t;
    float4 v = reinterpret_cast<const float4*>(s)[i];
    ushort4 o; o.x = f2bf(v.x); o.y = f2bf(v.y); o.z = f2bf(v.z); o.w = f2bf(v.w);
    reinterpret_cast<ushort4*>(d)[i] = o;
  } else if (blk < 38408) {
    int i = (blk - 32264) * 256 + t;
    int idx = i * 4;
    int n = idx / KXX, k = idx - n * KXX;
    const float* p = (k < 2560) ? (Wih + (size_t)n * 2560 + k) : (Whh + (size_t)n * HH + (k - 2560));
    float4 v = *reinterpret_cast<const float4*>(p);
    ushort4 o; o.x = f2bf(v.x); o.y = f2bf(v.y); o.z = f2bf(v.z); o.w = f2bf(v.w);
    reinterpret_cast<ushort4*>(Wc)[i] = o;
  } else {
    int i = (blk - 38408) * 256 + t;
    int idx = i * 4;
    int tt = idx / (BB * HH);
    int r = idx - tt * (BB * HH);
    int b = r / HH, k = r - b * HH;
    int tok = seq[b * 17 + tt];
    float4 v = *reinterpret_cast<const float4*>(emb + (size_t)tok * HH + k);
    ushort4 o; o.x = f2bf(v.x); o.y = f2bf(v.y); o.z = f2bf(v.z); o.w = f2bf(v.w);
    reinterpret_cast<ushort4*>(Xemb)[i] = o;
  }
}

// h0 = c0 = fc @ lin_W^T + lin_b  -> Xh slice 0 (bf16) and c (f32)
__global__ __launch_bounds__(256) void k_h0(const u16* __restrict__ fcb, const u16* __restrict__ linWb,
                                            const float* __restrict__ lin_b,
                                            u16* __restrict__ hb, float* __restrict__ c) {
  int lane = threadIdx.x & 63;
  int m0 = (threadIdx.x >> 6) * 16, n0 = blockIdx.x * 16;
  const u16* xr = fcb + (size_t)(m0 + (lane & 15)) * FF + ((lane >> 4) * 8);
  const u16* wr = linWb + (size_t)(n0 + (lane & 15)) * FF + ((lane >> 4) * 8);
  f32x4 acc = {0.f, 0.f, 0.f, 0.f};
#pragma unroll 8
  for (int kk = 0; kk < 64; ++kk)
    acc = mfma16(ldbf(xr + kk * 32), ldbf(wr + kk * 32), acc);
  int col = n0 + (lane & 15);
  float bias = lin_b[col];
#pragma unroll
  for (int j = 0; j < 4; ++j) {
    int row = m0 + (lane >> 4) * 4 + j;
    float v = acc[j] + bias;
    hb[row * HH + col] = f2bf(v);
    c[row * HH + col] = v;
  }
}

// p_att = att_feats @ ctx_W^T + ctx_b. 128x128 tile, 8 WAVES/block (3 waves/SIMD
// co-residency for barrier-drain hiding); XCD remap; gload_lds staging.
// Wave (wr2, wc2) owns 64 rows x 32 cols: 4x2 fragments.
__global__ __launch_bounds__(512) void k_patt(const u16* __restrict__ attb,
                                              const u16* __restrict__ ctxWb, const float* __restrict__ ctx_b,
                                              u16* __restrict__ p_att) {
  __shared__ __align__(16) u16 As[128][32];
  __shared__ __align__(16) u16 Bs[128][32];
  int d = blockIdx.x;
  int bid = (d & 7) * 49 + (d >> 3);     // 392 = 8*49, bijective XCD remap
  int mb = bid >> 2, nb = bid & 3;       // 98 x 4
  int m0 = mb * 128, n0 = nb * 128;
  int tid = threadIdx.x;                 // 0..511
  int wid = tid >> 6, lane = tid & 63;
  int wr2 = wid >> 2, wc2 = wid & 3;     // 2 row-halves x 4 col-quadrants
  int ar = lane & 15, ak = (lane >> 4) * 8;
  // staging: 512 threads x 16B = 8KB = one full A (or B) tile slab per shot
  const u16* ga = attb + (size_t)(m0 + (tid >> 2)) * FF + (tid & 3) * 8;
  const u16* gb = ctxWb + (size_t)(n0 + (tid >> 2)) * FF + (tid & 3) * 8;
  u16* la = &As[0][0] + tid * 8;
  u16* lb = &Bs[0][0] + tid * 8;

  f32x4 zero = {0.f, 0.f, 0.f, 0.f};
  f32x4 acc[4][2];
#pragma unroll
  for (int i = 0; i < 4; ++i)
#pragma unroll
    for (int j = 0; j < 2; ++j) acc[i][j] = zero;

  for (int ks = 0; ks < 64; ++ks) {
    int k0 = ks * 32;
    __syncthreads();
    gload16(ga + k0, la);
    gload16(gb + k0, lb);
    __syncthreads();
    short8 af[4], bfr[2];
#pragma unroll
    for (int i = 0; i < 4; ++i)
      af[i] = *reinterpret_cast<const short8*>(&As[wr2 * 64 + i * 16 + ar][ak]);
#pragma unroll
    for (int j = 0; j < 2; ++j)
      bfr[j] = *reinterpret_cast<const short8*>(&Bs[wc2 * 32 + j * 16 + ar][ak]);
#pragma unroll
    for (int i = 0; i < 4; ++i)
#pragma unroll
      for (int j = 0; j < 2; ++j)
        acc[i][j] = mfma16(af[i], bfr[j], acc[i][j]);
  }
#pragma unroll
  for (int j = 0; j < 2; ++j) {
    int col = n0 + wc2 * 32 + j * 16 + ar;
    float bias = ctx_b[col];
#pragma unroll
    for (int i = 0; i < 4; ++i)
#pragma unroll
      for (int q = 0; q < 4; ++q) {
        int row = m0 + wr2 * 64 + i * 16 + (lane >> 4) * 4 + q;
        p_att[(size_t)row * HH + col] = f2bf(acc[i][j][q] + bias);
      }
  }
}

// ---------------- per-step device bodies (R8/R11-proven) ----------------
__device__ __forceinline__ void dev_atth(int nt, const u16* __restrict__ hb, const u16* __restrict__ h2aWb,
                                         const float* __restrict__ h2ab, float* __restrict__ ah) {
  int lane = threadIdx.x & 63;
  int m0 = (threadIdx.x >> 6) * 16, n0 = nt * 16;
  int ak = (lane >> 4) * 8;
  const u16* xr = hb + (size_t)(m0 + (lane & 15)) * HH + ak;
  const u16* wr = h2aWb + (size_t)(n0 + (lane & 15)) * HH + ak;
  f32x4 acc = {0.f, 0.f, 0.f, 0.f};
#pragma unroll
  for (int kk = 0; kk < 16; ++kk)
    acc = mfma16(ldbf(xr + kk * 32), ldbf(wr + kk * 32), acc);
  int col = n0 + (lane & 15);
  float bias = h2ab[col];
#pragma unroll
  for (int j = 0; j < 4; ++j)
    ah[(size_t)(m0 + (lane >> 4) * 4 + j) * HH + col] = acc[j] + bias;
}

__device__ __forceinline__ void dev_e(int bid4, const u16* __restrict__ p_att, const float* __restrict__ ah,
                                      const float* __restrict__ alphaW, const float* __restrict__ alphab,
                                      float* __restrict__ e) {
  int gw = bid4 * 4 + (threadIdx.x >> 6);   // [0, 12544)
  int lane = threadIdx.x & 63;
  int b = gw / LL, l = gw - b * LL;
  short8 pa = ldbf(p_att + (size_t)gw * HH + lane * 8);
  const float4* ap = reinterpret_cast<const float4*>(ah + (size_t)b * HH + lane * 8);
  float4 a0 = ap[0], a1 = ap[1];
  const float4* wp = reinterpret_cast<const float4*>(alphaW + lane * 8);
  float4 w0 = wp[0], w1 = wp[1];
  float s = fast_tanh(bf2f((u16)pa[0]) + a0.x) * w0.x
          + fast_tanh(bf2f((u16)pa[1]) + a0.y) * w0.y
          + fast_tanh(bf2f((u16)pa[2]) + a0.z) * w0.z
          + fast_tanh(bf2f((u16)pa[3]) + a0.w) * w0.w
          + fast_tanh(bf2f((u16)pa[4]) + a1.x) * w1.x
          + fast_tanh(bf2f((u16)pa[5]) + a1.y) * w1.y
          + fast_tanh(bf2f((u16)pa[6]) + a1.z) * w1.z
          + fast_tanh(bf2f((u16)pa[7]) + a1.w) * w1.w;
  s = wred_sum(s);
  if (!lane) e[b * 256 + l] = s + alphab[0];
}

// ---------------- per-step kernels (4 per step, logits deferred) ----------------
__global__ __launch_bounds__(256) void k_atth(const u16* __restrict__ hb, const u16* __restrict__ h2aWb,
                                              const float* __restrict__ h2ab, float* __restrict__ ah) {
  dev_atth(blockIdx.x, hb, h2aWb, h2ab, ah);
}
__global__ __launch_bounds__(256) void k_e(const u16* __restrict__ p_att, const float* __restrict__ ah,
                                           const float* __restrict__ alphaW, const float* __restrict__ alphab,
                                           float* __restrict__ e) {
  dev_e(blockIdx.x, p_att, ah, alphaW, alphab, e);
}

// attR: softmax(e[b,:]) per block (redundant x8, cheap) then weighted sum.
// 512 blocks = b(64) x f-chunk(8) of 256 feats; 2 waves/SIMD for latency hiding.
__global__ __launch_bounds__(256) void k_attR(const float* __restrict__ e, const u16* __restrict__ attb,
                                              u16* __restrict__ xatt) {
  __shared__ float w_s[LL];
  __shared__ float red[8];
  __shared__ float part[4][256];
  int b = blockIdx.x >> 3, f8 = blockIdx.x & 7;
  int t = threadIdx.x, wid = t >> 6, lane = t & 63;
  float ev = (t < LL) ? e[b * 256 + t] : -1e30f;
  float m = wred_max(ev);
  if (!lane) red[wid] = m;
  __syncthreads();
  m = fmaxf(fmaxf(red[0], red[1]), fmaxf(red[2], red[3]));
  float ex = __expf(ev - m);
  float s = wred_sum(ex);
  if (!lane) red[4 + wid] = s;
  __syncthreads();
  s = red[4] + red[5] + red[6] + red[7];
  if (t < LL) w_s[t] = ex / s;
  __syncthreads();

  int f0 = f8 * 256 + lane * 4;
  float a0 = 0.f, a1 = 0.f, a2 = 0.f, a3 = 0.f;
  int l0 = wid * 49;
  const u16* ap = attb + ((size_t)(b * LL + l0)) * FF + f0;
#pragma unroll 7
  for (int l = 0; l < 49; ++l) {
    float wv = w_s[l0 + l];
    short4v av = *reinterpret_cast<const short4v*>(ap);
    ap += FF;
    a0 += wv * bf2f((u16)av[0]); a1 += wv * bf2f((u16)av[1]);
    a2 += wv * bf2f((u16)av[2]); a3 += wv * bf2f((u16)av[3]);
  }
  *reinterpret_cast<float4*>(&part[wid][lane * 4]) = make_float4(a0, a1, a2, a3);
  __syncthreads();
  float v = part[0][t] + part[1][t] + part[2][t] + part[3][t];
  xatt[(size_t)b * FF + f8 * 256 + t] = f2bf(v);
}

// gates+LSTM: 128 blocks = jt(32) x mq(4); 4 waves = K-quarters (proven)
__global__ __launch_bounds__(256) void k_gatelstm(const u16* __restrict__ Xemb, const u16* __restrict__ xatt,
                                                  const u16* __restrict__ hb_in, const u16* __restrict__ Wc,
                                                  float* __restrict__ c, u16* __restrict__ hb_out, int tstep) {
  __shared__ float sm[4][4][16][16];
  int jt = blockIdx.x >> 2, mq = blockIdx.x & 3;
  int m0 = mq * 16;
  int lane = threadIdx.x & 63, kq = threadIdx.x >> 6;
  int ar = lane & 15, ak8 = (lane >> 4) * 8;
  int m = m0 + ar;
  int wn = jt * 16 + ar;
  f32x4 zero = {0.f, 0.f, 0.f, 0.f};
  f32x4 acc[4] = {zero, zero, zero, zero};
  const u16* xr0 = Xemb + ((size_t)tstep * BB + m) * HH;
  const u16* xr1 = xatt + (size_t)m * FF;
  const u16* xr2 = hb_in + (size_t)m * HH;

#pragma unroll 4
  for (int kk = 0; kk < 24; ++kk) {
    int k = kq * 768 + kk * 32 + ak8;
    short8 a;
    if (k < 512)       a = ldbf(xr0 + k);
    else if (k < 2560) a = ldbf(xr1 + (k - 512));
    else               a = ldbf(xr2 + (k - 2560));
    short8 bv[4];
#pragma unroll
    for (int g = 0; g < 4; ++g)
      bv[g] = ldbf(Wc + (size_t)(g * 512 + wn) * KXX + k);
#pragma unroll
    for (int g = 0; g < 4; ++g) acc[g] = mfma16(a, bv[g], acc[g]);
  }
#pragma unroll
  for (int g = 0; g < 4; ++g)
#pragma unroll
    for (int q = 0; q < 4; ++q)
      sm[kq][g][(lane >> 4) * 4 + q][ar] = acc[g][q];
  __syncthreads();
  int r = threadIdx.x >> 4, cc = threadIdx.x & 15;
  float gi = sm[0][0][r][cc] + sm[1][0][r][cc] + sm[2][0][r][cc] + sm[3][0][r][cc];
  float gf = sm[0][1][r][cc] + sm[1][1][r][cc] + sm[2][1][r][cc] + sm[3][1][r][cc];
  float gg = sm[0][2][r][cc] + sm[1][2][r][cc] + sm[2][2][r][cc] + sm[3][2][r][cc];
  float go = sm[0][3][r][cc] + sm[1][3][r][cc] + sm[2][3][r][cc] + sm[3][3][r][cc];
  int idx = (m0 + r) * HH + jt * 16 + cc;
  float cn = fast_sig(gf) * c[idx] + fast_sig(gi) * fast_tanh(gg);
  float hn = fast_sig(go) * fast_tanh(cn);
  c[idx] = cn;
  hb_out[idx] = f2bf(hn);
}

// ---------------- deferred logits (writes straight into d_out; R10/R13-proven) ----------------
__global__ __launch_bounds__(256) void k_logall(const u16* __restrict__ XhL, const u16* __restrict__ lWb,
                                                const float* __restrict__ lb, float* __restrict__ out) {
  __shared__ __align__(16) u16 As[128][32];
  __shared__ __align__(16) u16 Bs[128][32];
  int d = blockIdx.x;
  int mb = d & 7, nb = d >> 3;
  int m0 = mb * 128, n0 = nb * 128;
  int tid = threadIdx.x;
  int wid = tid >> 6, lane = tid & 63;
  int wr = wid >> 1, wc = wid & 1;
  int ar = lane & 15, ak = (lane >> 4) * 8;
  int rt = tid >> 1, st = tid & 1;
  const u16* agp = XhL + (size_t)(m0 + rt) * HH + st * 16;
  const u16* bgp = lWb + (size_t)(n0 + rt) * HH + st * 16;

  f32x4 zero = {0.f, 0.f, 0.f, 0.f};
  f32x4 acc[4][4];
#pragma unroll
  for (int i = 0; i < 4; ++i)
#pragma unroll
    for (int j = 0; j < 4; ++j) acc[i][j] = zero;

  for (int ks = 0; ks < 16; ++ks) {
    int k0 = ks * 32;
    short8 a0 = ldbf(agp + k0);
    short8 a1 = ldbf(agp + k0 + 8);
    short8 b0 = ldbf(bgp + k0);
    short8 b1 = ldbf(bgp + k0 + 8);
    __syncthreads();
    *reinterpret_cast<short8*>(&As[rt][st * 16]) = a0;
    *reinterpret_cast<short8*>(&As[rt][st * 16 + 8]) = a1;
    *reinterpret_cast<short8*>(&Bs[rt][st * 16]) = b0;
    *reinterpret_cast<short8*>(&Bs[rt][st * 16 + 8]) = b1;
    __syncthreads();
    short8 af[4], bfr[4];
#pragma unroll
    for (int i = 0; i < 4; ++i)
      af[i] = *reinterpret_cast<const short8*>(&As[wr * 64 + i * 16 + ar][ak]);
#pragma unroll
    for (int j = 0; j < 4; ++j)
      bfr[j] = *reinterpret_cast<const short8*>(&Bs[wc * 64 + j * 16 + ar][ak]);
#pragma unroll
    for (int i = 0; i < 4; ++i)
#pragma unroll
      for (int j = 0; j < 4; ++j)
        acc[i][j] = mfma16(af[i], bfr[j], acc[i][j]);
  }
#pragma unroll
  for (int j = 0; j < 4; ++j) {
    int col = n0 + wc * 64 + j * 16 + ar;
    if (col >= VV) continue;
    float bias = lb[col];
#pragma unroll
    for (int i = 0; i < 4; ++i)
#pragma unroll
      for (int q = 0; q < 4; ++q) {
        int row = m0 + wr * 64 + i * 16 + (lane >> 4) * 4 + q;
        int bb = row & 63, ts = row >> 6;
        out[((size_t)(bb * TT + ts)) * VV + col] = acc[i][j][q] + bias;
      }
  }
}

// in-place log-softmax on all 1024 out rows (R10/R13-proven)
__global__ __launch_bounds__(256) void k_lsmall(float* __restrict__ out) {
  __shared__ float red[8];
  float* row = out + (size_t)blockIdx.x * VV;
  float4* row4 = reinterpret_cast<float4*>(row);
  int t = threadIdx.x, wid = t >> 6, lane = t & 63;
  float4 v[10];
  float m = -1e30f;
#pragma unroll
  for (int p = 0; p < 10; ++p) {
    int i4 = p * 256 + t;
    if (i4 < VV / 4) {
      v[p] = row4[i4];
      m = fmaxf(m, fmaxf(fmaxf(v[p].x, v[p].y), fmaxf(v[p].z, v[p].w)));
    } else {
      v[p] = make_float4(-1e30f, -1e30f, -1e30f, -1e30f);
    }
  }
  m = wred_max(m);
  if (!lane) red[wid] = m;
  __syncthreads();
  m = fmaxf(fmaxf(red[0], red[1]), fmaxf(red[2], red[3]));
  float s = 0.f;
#pragma unroll
  for (int p = 0; p < 10; ++p)
    s += __expf(v[p].x - m) + __expf(v[p].y - m) + __expf(v[p].z - m) + __expf(v[p].w - m);
  s = wred_sum(s);
  if (!lane) red[4 + wid] = s;
  __syncthreads();
  s = red[4] + red[5] + red[6] + red[7];
  float lse = m + __logf(s);
#pragma unroll
  for (int p = 0; p < 10; ++p) {
    int i4 = p * 256 + t;
    if (i4 < VV / 4)
      row4[i4] = make_float4(v[p].x - lse, v[p].y - lse, v[p].z - lse, v[p].w - lse);
  }
}

// ---------------- host ----------------
extern "C" void kernel_launch(void* const* d_in, const int* in_sizes, int n_in,
                              void* d_out, int out_size, void* d_ws, size_t ws_size,
                              hipStream_t stream) {
  const float* fc      = (const float*)d_in[0];
  const float* attf    = (const float*)d_in[1];
  const int*   seq     = (const int*)d_in[2];
  const float* lin_W   = (const float*)d_in[3];
  const float* lin_b   = (const float*)d_in[4];
  const float* emb     = (const float*)d_in[5];
  const float* Wih     = (const float*)d_in[6];
  const float* Whh     = (const float*)d_in[7];
  const float* ctx_W   = (const float*)d_in[8];
  const float* ctx_b   = (const float*)d_in[9];
  const float* h2a_W   = (const float*)d_in[10];
  const float* h2a_b   = (const float*)d_in[11];
  const float* alpha_W = (const float*)d_in[12];
  const float* alpha_b = (const float*)d_in[13];
  const float* logit_W = (const float*)d_in[14];
  const float* logit_b = (const float*)d_in[15];
  float* out = (float*)d_out;

  char* base = (char*)d_ws;
  size_t off = 0;
  auto alloc = [&](size_t bytes) -> char* {
    off = (off + 255) & ~(size_t)255;
    char* p = base + off;
    off += bytes;
    return p;
  };
  // footprint ~90.3 MiB (proven to fit)
  u16*   p_att  = (u16*)alloc((size_t)MM * HH * 2);
  u16*   ctxWb  = (u16*)alloc((size_t)HH * FF * 2);
  u16*   linWb  = (u16*)alloc((size_t)HH * FF * 2);
  u16*   fcb    = (u16*)alloc((size_t)BB * FF * 2);
  u16*   h2aWb  = (u16*)alloc((size_t)HH * HH * 2);
  u16*   Xemb   = (u16*)alloc((size_t)TT * BB * HH * 2);
  float* c      = (float*)alloc((size_t)BB * HH * 4);
  u16*   Xh     = (u16*)alloc((size_t)(TT + 1) * BB * HH * 2);   // slice 0 = h0
  u16*   xatt   = (u16*)alloc((size_t)BB * FF * 2);
  float* eb     = (float*)alloc((size_t)BB * 256 * 4);
  float* ah     = (float*)alloc((size_t)BB * HH * 4);
  u16*   Wc     = (u16*)alloc((size_t)2048 * KXX * 2);
  u16*   lWb    = (u16*)alloc((size_t)NPAD * HH * 2);   // pad rows: finite poison, never stored
  u16*   attb   = (u16*)alloc((size_t)MM * FF * 2);
  (void)ws_size;

  k_setup<<<38920, 256, 0, stream>>>(ctx_W, ctxWb, lin_W, linWb, h2a_W, h2aWb, logit_W, lWb,
                                     fc, fcb, attf, attb, Wih, Whh, Wc, emb, seq, Xemb);
  k_h0<<<32, 256, 0, stream>>>(fcb, linWb, lin_b, Xh, c);
  k_patt<<<392, 512, 0, stream>>>(attb, ctxWb, ctx_b, p_att);

  // prologue: ah(0), e(0)
  k_atth<<<32, 256, 0, stream>>>(Xh, h2aWb, h2a_b, ah);
  k_e<<<MM / 4, 256, 0, stream>>>(p_att, ah, alpha_W, alpha_b, eb);

  for (int t = 0; t < TT; ++t) {
    u16* ht  = Xh + (size_t)t * BB * HH;
    u16* htn = Xh + (size_t)(t + 1) * BB * HH;
    k_attR<<<512, 256, 0, stream>>>(eb, attb, xatt);
    k_gatelstm<<<128, 256, 0, stream>>>(Xemb, xatt, ht, Wc, c, htn, t);
    if (t < TT - 1) {
      k_atth<<<32, 256, 0, stream>>>(htn, h2aWb, h2a_b, ah);
      k_e<<<MM / 4, 256, 0, stream>>>(p_att, ah, alpha_W, alpha_b, eb);
    }
  }
  k_logall<<<600, 256, 0, stream>>>(Xh + (size_t)BB * HH, lWb, logit_b, out);
  k_lsmall<<<TT * BB, 256, 0, stream>>>(out);
}

// Round 15
// 769.051 us; speedup vs baseline: 1.1865x; 1.0251x over previous
//
#include <hip/hip_runtime.h>
#include <stdint.h>
#include <stddef.h>

#define BB 64
#define LL 196
#define FF 2048
#define HH 512
#define VV 9488
#define NPAD 9600        // lWb padded rows; pad rows stay finite poison, never stored
#define TT 16
#define KXX 3072         // H + F + H (x' = [xt, att_res, h])
#define MM (BB * LL)     // 12544
#define SETUP_TOT 4981760  // total 8-elem units across all setup regions

typedef short short8 __attribute__((ext_vector_type(8)));
typedef short short4v __attribute__((ext_vector_type(4)));
typedef float f32x4 __attribute__((ext_vector_type(4)));
typedef unsigned short u16;

typedef __attribute__((address_space(3))) uint32_t lds_u32_t;
typedef __attribute__((address_space(1))) const uint32_t glb_u32_t;

__device__ __forceinline__ u16 f2bf(float f) {
  uint32_t u = __builtin_bit_cast(uint32_t, f);
  u += 0x7FFFu + ((u >> 16) & 1u);   // RNE
  return (u16)(u >> 16);
}
__device__ __forceinline__ float bf2f(u16 s) {
  return __builtin_bit_cast(float, ((uint32_t)s) << 16);
}
__device__ __forceinline__ float fast_tanh(float x) {
  return 1.0f - 2.0f / (1.0f + __expf(2.0f * x));
}
__device__ __forceinline__ float fast_sig(float x) {
  return 1.0f / (1.0f + __expf(-x));
}
__device__ __forceinline__ float wred_sum(float v) {
#pragma unroll
  for (int o = 32; o; o >>= 1) v += __shfl_xor(v, o, 64);
  return v;
}
__device__ __forceinline__ float wred_max(float v) {
#pragma unroll
  for (int o = 32; o; o >>= 1) v = fmaxf(v, __shfl_xor(v, o, 64));
  return v;
}
__device__ __forceinline__ f32x4 mfma16(short8 a, short8 b, f32x4 c) {
  return __builtin_amdgcn_mfma_f32_16x16x32_bf16(a, b, c, 0, 0, 0);
}
__device__ __forceinline__ short8 ldbf(const u16* p) {
  return *reinterpret_cast<const short8*>(p);
}
// async global->LDS, 16B per lane; lds addr must be wave-base + lane*16 (linear)
__device__ __forceinline__ void gload16(const u16* g, u16* l) {
  __builtin_amdgcn_global_load_lds((glb_u32_t*)g, (lds_u32_t*)l, 16, 0, 0);
}

// ---------------- one fused setup kernel: grid-stride, 32B/thread/iter ----------------
// regions in 8-elem units:
// ctx[0,131072) lin[131072,262144) h2a[262144,294912) logit[294912,902144)
// fc[902144,918528) attf[918528,4129792) wc[4129792,4916224) xemb[4916224,4981760)
__global__ __launch_bounds__(256) void k_setup(
    const float* __restrict__ ctx_W, u16* __restrict__ ctxWb,
    const float* __restrict__ lin_W, u16* __restrict__ linWb,
    const float* __restrict__ h2a_W, u16* __restrict__ h2aWb,
    const float* __restrict__ logit_W, u16* __restrict__ lWb,
    const float* __restrict__ fc, u16* __restrict__ fcb,
    const float* __restrict__ attf, u16* __restrict__ attb,
    const float* __restrict__ Wih, const float* __restrict__ Whh, u16* __restrict__ Wc,
    const float* __restrict__ emb, const int* __restrict__ seq, u16* __restrict__ Xemb) {
  size_t stride = (size_t)gridDim.x * 256;
  for (size_t i = (size_t)blockIdx.x * 256 + threadIdx.x; i < SETUP_TOT; i += stride) {
    float4 v0, v1;
    u16* dp;
    if (i < 4129792) {
      const float* s; u16* d; size_t rel;
      if (i < 131072)      { s = ctx_W;   d = ctxWb; rel = i; }
      else if (i < 262144) { s = lin_W;   d = linWb; rel = i - 131072; }
      else if (i < 294912) { s = h2a_W;   d = h2aWb; rel = i - 262144; }
      else if (i < 902144) { s = logit_W; d = lWb;   rel = i - 294912; }
      else if (i < 918528) { s = fc;      d = fcb;   rel = i - 902144; }
      else                 { s = attf;    d = attb;  rel = i - 918528; }
      size_t idx = rel * 8;
      v0 = *reinterpret_cast<const float4*>(s + idx);
      v1 = *reinterpret_cast<const float4*>(s + idx + 4);
      dp = d + idx;
    } else if (i < 4916224) {
      size_t idx = (i - 4129792) * 8;
      int n = (int)(idx / KXX), k = (int)(idx - (size_t)n * KXX);
      const float* p = (k < 2560) ? (Wih + (size_t)n * 2560 + k) : (Whh + (size_t)n * HH + (k - 2560));
      v0 = *reinterpret_cast<const float4*>(p);
      v1 = *reinterpret_cast<const float4*>(p + 4);
      dp = Wc + idx;
    } else {
      size_t idx = (i - 4916224) * 8;
      int tt = (int)(idx / (BB * HH));
      int r = (int)(idx - (size_t)tt * (BB * HH));
      int b = r / HH, k = r - b * HH;
      int tok = seq[b * 17 + tt];
      const float* p = emb + (size_t)tok * HH + k;
      v0 = *reinterpret_cast<const float4*>(p);
      v1 = *reinterpret_cast<const float4*>(p + 4);
      dp = Xemb + idx;
    }
    short8 o;
    o[0] = (short)f2bf(v0.x); o[1] = (short)f2bf(v0.y); o[2] = (short)f2bf(v0.z); o[3] = (short)f2bf(v0.w);
    o[4] = (short)f2bf(v1.x); o[5] = (short)f2bf(v1.y); o[6] = (short)f2bf(v1.z); o[7] = (short)f2bf(v1.w);
    *reinterpret_cast<short8*>(dp) = o;
  }
}

// h0 = c0 = fc @ lin_W^T + lin_b  -> Xh slice 0 (bf16) and c (f32)
__global__ __launch_bounds__(256) void k_h0(const u16* __restrict__ fcb, const u16* __restrict__ linWb,
                                            const float* __restrict__ lin_b,
                                            u16* __restrict__ hb, float* __restrict__ c) {
  int lane = threadIdx.x & 63;
  int m0 = (threadIdx.x >> 6) * 16, n0 = blockIdx.x * 16;
  const u16* xr = fcb + (size_t)(m0 + (lane & 15)) * FF + ((lane >> 4) * 8);
  const u16* wr = linWb + (size_t)(n0 + (lane & 15)) * FF + ((lane >> 4) * 8);
  f32x4 acc = {0.f, 0.f, 0.f, 0.f};
#pragma unroll 8
  for (int kk = 0; kk < 64; ++kk)
    acc = mfma16(ldbf(xr + kk * 32), ldbf(wr + kk * 32), acc);
  int col = n0 + (lane & 15);
  float bias = lin_b[col];
#pragma unroll
  for (int j = 0; j < 4; ++j) {
    int row = m0 + (lane >> 4) * 4 + j;
    float v = acc[j] + bias;
    hb[row * HH + col] = f2bf(v);
    c[row * HH + col] = v;
  }
}

// p_att = att_feats @ ctx_W^T + ctx_b. 128x128 tile, 8 waves/block (R14-proven);
// XCD remap; gload_lds staging.
__global__ __launch_bounds__(512) void k_patt(const u16* __restrict__ attb,
                                              const u16* __restrict__ ctxWb, const float* __restrict__ ctx_b,
                                              u16* __restrict__ p_att) {
  __shared__ __align__(16) u16 As[128][32];
  __shared__ __align__(16) u16 Bs[128][32];
  int d = blockIdx.x;
  int bid = (d & 7) * 49 + (d >> 3);     // 392 = 8*49, bijective XCD remap
  int mb = bid >> 2, nb = bid & 3;       // 98 x 4
  int m0 = mb * 128, n0 = nb * 128;
  int tid = threadIdx.x;                 // 0..511
  int wid = tid >> 6, lane = tid & 63;
  int wr2 = wid >> 2, wc2 = wid & 3;     // 2 row-halves x 4 col-quadrants
  int ar = lane & 15, ak = (lane >> 4) * 8;
  const u16* ga = attb + (size_t)(m0 + (tid >> 2)) * FF + (tid & 3) * 8;
  const u16* gb = ctxWb + (size_t)(n0 + (tid >> 2)) * FF + (tid & 3) * 8;
  u16* la = &As[0][0] + tid * 8;
  u16* lb = &Bs[0][0] + tid * 8;

  f32x4 zero = {0.f, 0.f, 0.f, 0.f};
  f32x4 acc[4][2];
#pragma unroll
  for (int i = 0; i < 4; ++i)
#pragma unroll
    for (int j = 0; j < 2; ++j) acc[i][j] = zero;

  for (int ks = 0; ks < 64; ++ks) {
    int k0 = ks * 32;
    __syncthreads();
    gload16(ga + k0, la);
    gload16(gb + k0, lb);
    __syncthreads();
    short8 af[4], bfr[2];
#pragma unroll
    for (int i = 0; i < 4; ++i)
      af[i] = *reinterpret_cast<const short8*>(&As[wr2 * 64 + i * 16 + ar][ak]);
#pragma unroll
    for (int j = 0; j < 2; ++j)
      bfr[j] = *reinterpret_cast<const short8*>(&Bs[wc2 * 32 + j * 16 + ar][ak]);
#pragma unroll
    for (int i = 0; i < 4; ++i)
#pragma unroll
      for (int j = 0; j < 2; ++j)
        acc[i][j] = mfma16(af[i], bfr[j], acc[i][j]);
  }
#pragma unroll
  for (int j = 0; j < 2; ++j) {
    int col = n0 + wc2 * 32 + j * 16 + ar;
    float bias = ctx_b[col];
#pragma unroll
    for (int i = 0; i < 4; ++i)
#pragma unroll
      for (int q = 0; q < 4; ++q) {
        int row = m0 + wr2 * 64 + i * 16 + (lane >> 4) * 4 + q;
        p_att[(size_t)row * HH + col] = f2bf(acc[i][j][q] + bias);
      }
  }
}

// ---------------- per-step device bodies (proven) ----------------
__device__ __forceinline__ void dev_atth(int nt, const u16* __restrict__ hb, const u16* __restrict__ h2aWb,
                                         const float* __restrict__ h2ab, float* __restrict__ ah) {
  int lane = threadIdx.x & 63;
  int m0 = (threadIdx.x >> 6) * 16, n0 = nt * 16;
  int ak = (lane >> 4) * 8;
  const u16* xr = hb + (size_t)(m0 + (lane & 15)) * HH + ak;
  const u16* wr = h2aWb + (size_t)(n0 + (lane & 15)) * HH + ak;
  f32x4 acc = {0.f, 0.f, 0.f, 0.f};
#pragma unroll
  for (int kk = 0; kk < 16; ++kk)
    acc = mfma16(ldbf(xr + kk * 32), ldbf(wr + kk * 32), acc);
  int col = n0 + (lane & 15);
  float bias = h2ab[col];
#pragma unroll
  for (int j = 0; j < 4; ++j)
    ah[(size_t)(m0 + (lane >> 4) * 4 + j) * HH + col] = acc[j] + bias;
}

__device__ __forceinline__ void dev_e(int bid4, const u16* __restrict__ p_att, const float* __restrict__ ah,
                                      const float* __restrict__ alphaW, const float* __restrict__ alphab,
                                      float* __restrict__ e) {
  int gw = bid4 * 4 + (threadIdx.x >> 6);   // [0, 12544)
  int lane = threadIdx.x & 63;
  int b = gw / LL, l = gw - b * LL;
  short8 pa = ldbf(p_att + (size_t)gw * HH + lane * 8);
  const float4* ap = reinterpret_cast<const float4*>(ah + (size_t)b * HH + lane * 8);
  float4 a0 = ap[0], a1 = ap[1];
  const float4* wp = reinterpret_cast<const float4*>(alphaW + lane * 8);
  float4 w0 = wp[0], w1 = wp[1];
  float s = fast_tanh(bf2f((u16)pa[0]) + a0.x) * w0.x
          + fast_tanh(bf2f((u16)pa[1]) + a0.y) * w0.y
          + fast_tanh(bf2f((u16)pa[2]) + a0.z) * w0.z
          + fast_tanh(bf2f((u16)pa[3]) + a0.w) * w0.w
          + fast_tanh(bf2f((u16)pa[4]) + a1.x) * w1.x
          + fast_tanh(bf2f((u16)pa[5]) + a1.y) * w1.y
          + fast_tanh(bf2f((u16)pa[6]) + a1.z) * w1.z
          + fast_tanh(bf2f((u16)pa[7]) + a1.w) * w1.w;
  s = wred_sum(s);
  if (!lane) e[b * 256 + l] = s + alphab[0];
}

// ---------------- per-step kernels (4 per step, logits deferred) ----------------
__global__ __launch_bounds__(256) void k_atth(const u16* __restrict__ hb, const u16* __restrict__ h2aWb,
                                              const float* __restrict__ h2ab, float* __restrict__ ah) {
  dev_atth(blockIdx.x, hb, h2aWb, h2ab, ah);
}
__global__ __launch_bounds__(256) void k_e(const u16* __restrict__ p_att, const float* __restrict__ ah,
                                           const float* __restrict__ alphaW, const float* __restrict__ alphab,
                                           float* __restrict__ e) {
  dev_e(blockIdx.x, p_att, ah, alphaW, alphab, e);
}

// attR: softmax(e[b,:]) per block (redundant x8, cheap) then weighted sum.
// 512 blocks = b(64) x f-chunk(8) of 256 feats (R14-proven).
__global__ __launch_bounds__(256) void k_attR(const float* __restrict__ e, const u16* __restrict__ attb,
                                              u16* __restrict__ xatt) {
  __shared__ float w_s[LL];
  __shared__ float red[8];
  __shared__ float part[4][256];
  int b = blockIdx.x >> 3, f8 = blockIdx.x & 7;
  int t = threadIdx.x, wid = t >> 6, lane = t & 63;
  float ev = (t < LL) ? e[b * 256 + t] : -1e30f;
  float m = wred_max(ev);
  if (!lane) red[wid] = m;
  __syncthreads();
  m = fmaxf(fmaxf(red[0], red[1]), fmaxf(red[2], red[3]));
  float ex = __expf(ev - m);
  float s = wred_sum(ex);
  if (!lane) red[4 + wid] = s;
  __syncthreads();
  s = red[4] + red[5] + red[6] + red[7];
  if (t < LL) w_s[t] = ex / s;
  __syncthreads();

  int f0 = f8 * 256 + lane * 4;
  float a0 = 0.f, a1 = 0.f, a2 = 0.f, a3 = 0.f;
  int l0 = wid * 49;
  const u16* ap = attb + ((size_t)(b * LL + l0)) * FF + f0;
#pragma unroll 7
  for (int l = 0; l < 49; ++l) {
    float wv = w_s[l0 + l];
    short4v av = *reinterpret_cast<const short4v*>(ap);
    ap += FF;
    a0 += wv * bf2f((u16)av[0]); a1 += wv * bf2f((u16)av[1]);
    a2 += wv * bf2f((u16)av[2]); a3 += wv * bf2f((u16)av[3]);
  }
  *reinterpret_cast<float4*>(&part[wid][lane * 4]) = make_float4(a0, a1, a2, a3);
  __syncthreads();
  float v = part[0][t] + part[1][t] + part[2][t] + part[3][t];
  xatt[(size_t)b * FF + f8 * 256 + t] = f2bf(v);
}

// gates+LSTM: 128 blocks; XCD-dedup remap so the 4 mq-blocks sharing a jt's
// weight rows land on ONE XCD (L2 fetches the 1.6MB slice once, not 4x).
__global__ __launch_bounds__(256) void k_gatelstm(const u16* __restrict__ Xemb, const u16* __restrict__ xatt,
                                                  const u16* __restrict__ hb_in, const u16* __restrict__ Wc,
                                                  float* __restrict__ c, u16* __restrict__ hb_out, int tstep) {
  __shared__ float sm[4][4][16][16];
  int d = blockIdx.x;
  int bid = (d & 7) * 16 + (d >> 3);     // bijective: XCD x hosts jt in [x*4, x*4+4)
  int jt = bid >> 2, mq = bid & 3;
  int m0 = mq * 16;
  int lane = threadIdx.x & 63, kq = threadIdx.x >> 6;
  int ar = lane & 15, ak8 = (lane >> 4) * 8;
  int m = m0 + ar;
  int wn = jt * 16 + ar;
  f32x4 zero = {0.f, 0.f, 0.f, 0.f};
  f32x4 acc[4] = {zero, zero, zero, zero};
  const u16* xr0 = Xemb + ((size_t)tstep * BB + m) * HH;
  const u16* xr1 = xatt + (size_t)m * FF;
  const u16* xr2 = hb_in + (size_t)m * HH;

#pragma unroll 4
  for (int kk = 0; kk < 24; ++kk) {
    int k = kq * 768 + kk * 32 + ak8;
    short8 a;
    if (k < 512)       a = ldbf(xr0 + k);
    else if (k < 2560) a = ldbf(xr1 + (k - 512));
    else               a = ldbf(xr2 + (k - 2560));
    short8 bv[4];
#pragma unroll
    for (int g = 0; g < 4; ++g)
      bv[g] = ldbf(Wc + (size_t)(g * 512 + wn) * KXX + k);
#pragma unroll
    for (int g = 0; g < 4; ++g) acc[g] = mfma16(a, bv[g], acc[g]);
  }
#pragma unroll
  for (int g = 0; g < 4; ++g)
#pragma unroll
    for (int q = 0; q < 4; ++q)
      sm[kq][g][(lane >> 4) * 4 + q][ar] = acc[g][q];
  __syncthreads();
  int r = threadIdx.x >> 4, cc = threadIdx.x & 15;
  float gi = sm[0][0][r][cc] + sm[1][0][r][cc] + sm[2][0][r][cc] + sm[3][0][r][cc];
  float gf = sm[0][1][r][cc] + sm[1][1][r][cc] + sm[2][1][r][cc] + sm[3][1][r][cc];
  float gg = sm[0][2][r][cc] + sm[1][2][r][cc] + sm[2][2][r][cc] + sm[3][2][r][cc];
  float go = sm[0][3][r][cc] + sm[1][3][r][cc] + sm[2][3][r][cc] + sm[3][3][r][cc];
  int idx = (m0 + r) * HH + jt * 16 + cc;
  float cn = fast_sig(gf) * c[idx] + fast_sig(gi) * fast_tanh(gg);
  float hn = fast_sig(go) * fast_tanh(cn);
  c[idx] = cn;
  hb_out[idx] = f2bf(hn);
}

// ---------------- deferred logits (writes straight into d_out; proven) ----------------
__global__ __launch_bounds__(256) void k_logall(const u16* __restrict__ XhL, const u16* __restrict__ lWb,
                                                const float* __restrict__ lb, float* __restrict__ out) {
  __shared__ __align__(16) u16 As[128][32];
  __shared__ __align__(16) u16 Bs[128][32];
  int d = blockIdx.x;
  int mb = d & 7, nb = d >> 3;
  int m0 = mb * 128, n0 = nb * 128;
  int tid = threadIdx.x;
  int wid = tid >> 6, lane = tid & 63;
  int wr = wid >> 1, wc = wid & 1;
  int ar = lane & 15, ak = (lane >> 4) * 8;
  int rt = tid >> 1, st = tid & 1;
  const u16* agp = XhL + (size_t)(m0 + rt) * HH + st * 16;
  const u16* bgp = lWb + (size_t)(n0 + rt) * HH + st * 16;

  f32x4 zero = {0.f, 0.f, 0.f, 0.f};
  f32x4 acc[4][4];
#pragma unroll
  for (int i = 0; i < 4; ++i)
#pragma unroll
    for (int j = 0; j < 4; ++j) acc[i][j] = zero;

  for (int ks = 0; ks < 16; ++ks) {
    int k0 = ks * 32;
    short8 a0 = ldbf(agp + k0);
    short8 a1 = ldbf(agp + k0 + 8);
    short8 b0 = ldbf(bgp + k0);
    short8 b1 = ldbf(bgp + k0 + 8);
    __syncthreads();
    *reinterpret_cast<short8*>(&As[rt][st * 16]) = a0;
    *reinterpret_cast<short8*>(&As[rt][st * 16 + 8]) = a1;
    *reinterpret_cast<short8*>(&Bs[rt][st * 16]) = b0;
    *reinterpret_cast<short8*>(&Bs[rt][st * 16 + 8]) = b1;
    __syncthreads();
    short8 af[4], bfr[4];
#pragma unroll
    for (int i = 0; i < 4; ++i)
      af[i] = *reinterpret_cast<const short8*>(&As[wr * 64 + i * 16 + ar][ak]);
#pragma unroll
    for (int j = 0; j < 4; ++j)
      bfr[j] = *reinterpret_cast<const short8*>(&Bs[wc * 64 + j * 16 + ar][ak]);
#pragma unroll
    for (int i = 0; i < 4; ++i)
#pragma unroll
      for (int j = 0; j < 4; ++j)
        acc[i][j] = mfma16(af[i], bfr[j], acc[i][j]);
  }
#pragma unroll
  for (int j = 0; j < 4; ++j) {
    int col = n0 + wc * 64 + j * 16 + ar;
    if (col >= VV) continue;
    float bias = lb[col];
#pragma unroll
    for (int i = 0; i < 4; ++i)
#pragma unroll
      for (int q = 0; q < 4; ++q) {
        int row = m0 + wr * 64 + i * 16 + (lane >> 4) * 4 + q;
        int bb = row & 63, ts = row >> 6;
        out[((size_t)(bb * TT + ts)) * VV + col] = acc[i][j][q] + bias;
      }
  }
}

// in-place log-softmax on all 1024 out rows (proven)
__global__ __launch_bounds__(256) void k_lsmall(float* __restrict__ out) {
  __shared__ float red[8];
  float* row = out + (size_t)blockIdx.x * VV;
  float4* row4 = reinterpret_cast<float4*>(row);
  int t = threadIdx.x, wid = t >> 6, lane = t & 63;
  float4 v[10];
  float m = -1e30f;
#pragma unroll
  for (int p = 0; p < 10; ++p) {
    int i4 = p * 256 + t;
    if (i4 < VV / 4) {
      v[p] = row4[i4];
      m = fmaxf(m, fmaxf(fmaxf(v[p].x, v[p].y), fmaxf(v[p].z, v[p].w)));
    } else {
      v[p] = make_float4(-1e30f, -1e30f, -1e30f, -1e30f);
    }
  }
  m = wred_max(m);
  if (!lane) red[wid] = m;
  __syncthreads();
  m = fmaxf(fmaxf(red[0], red[1]), fmaxf(red[2], red[3]));
  float s = 0.f;
#pragma unroll
  for (int p = 0; p < 10; ++p)
    s += __expf(v[p].x - m) + __expf(v[p].y - m) + __expf(v[p].z - m) + __expf(v[p].w - m);
  s = wred_sum(s);
  if (!lane) red[4 + wid] = s;
  __syncthreads();
  s = red[4] + red[5] + red[6] + red[7];
  float lse = m + __logf(s);
#pragma unroll
  for (int p = 0; p < 10; ++p) {
    int i4 = p * 256 + t;
    if (i4 < VV / 4)
      row4[i4] = make_float4(v[p].x - lse, v[p].y - lse, v[p].z - lse, v[p].w - lse);
  }
}

// ---------------- host ----------------
extern "C" void kernel_launch(void* const* d_in, const int* in_sizes, int n_in,
                              void* d_out, int out_size, void* d_ws, size_t ws_size,
                              hipStream_t stream) {
  const float* fc      = (const float*)d_in[0];
  const float* attf    = (const float*)d_in[1];
  const int*   seq     = (const int*)d_in[2];
  const float* lin_W   = (const float*)d_in[3];
  const float* lin_b   = (const float*)d_in[4];
  const float* emb     = (const float*)d_in[5];
  const float* Wih     = (const float*)d_in[6];
  const float* Whh     = (const float*)d_in[7];
  const float* ctx_W   = (const float*)d_in[8];
  const float* ctx_b   = (const float*)d_in[9];
  const float* h2a_W   = (const float*)d_in[10];
  const float* h2a_b   = (const float*)d_in[11];
  const float* alpha_W = (const float*)d_in[12];
  const float* alpha_b = (const float*)d_in[13];
  const float* logit_W = (const float*)d_in[14];
  const float* logit_b = (const float*)d_in[15];
  float* out = (float*)d_out;

  char* base = (char*)d_ws;
  size_t off = 0;
  auto alloc = [&](size_t bytes) -> char* {
    off = (off + 255) & ~(size_t)255;
    char* p = base + off;
    off += bytes;
    return p;
  };
  // footprint ~90.3 MiB (proven to fit)
  u16*   p_att  = (u16*)alloc((size_t)MM * HH * 2);
  u16*   ctxWb  = (u16*)alloc((size_t)HH * FF * 2);
  u16*   linWb  = (u16*)alloc((size_t)HH * FF * 2);
  u16*   fcb    = (u16*)alloc((size_t)BB * FF * 2);
  u16*   h2aWb  = (u16*)alloc((size_t)HH * HH * 2);
  u16*   Xemb   = (u16*)alloc((size_t)TT * BB * HH * 2);
  float* c      = (float*)alloc((size_t)BB * HH * 4);
  u16*   Xh     = (u16*)alloc((size_t)(TT + 1) * BB * HH * 2);   // slice 0 = h0
  u16*   xatt   = (u16*)alloc((size_t)BB * FF * 2);
  float* eb     = (float*)alloc((size_t)BB * 256 * 4);
  float* ah     = (float*)alloc((size_t)BB * HH * 4);
  u16*   Wc     = (u16*)alloc((size_t)2048 * KXX * 2);
  u16*   lWb    = (u16*)alloc((size_t)NPAD * HH * 2);   // pad rows: finite poison, never stored
  u16*   attb   = (u16*)alloc((size_t)MM * FF * 2);
  (void)ws_size;

  k_setup<<<2048, 256, 0, stream>>>(ctx_W, ctxWb, lin_W, linWb, h2a_W, h2aWb, logit_W, lWb,
                                    fc, fcb, attf, attb, Wih, Whh, Wc, emb, seq, Xemb);
  k_h0<<<32, 256, 0, stream>>>(fcb, linWb, lin_b, Xh, c);
  k_patt<<<392, 512, 0, stream>>>(attb, ctxWb, ctx_b, p_att);

  // prologue: ah(0), e(0)
  k_atth<<<32, 256, 0, stream>>>(Xh, h2aWb, h2a_b, ah);
  k_e<<<MM / 4, 256, 0, stream>>>(p_att, ah, alpha_W, alpha_b, eb);

  for (int t = 0; t < TT; ++t) {
    u16* ht  = Xh + (size_t)t * BB * HH;
    u16* htn = Xh + (size_t)(t + 1) * BB * HH;
    k_attR<<<512, 256, 0, stream>>>(eb, attb, xatt);
    k_gatelstm<<<128, 256, 0, stream>>>(Xemb, xatt, ht, Wc, c, htn, t);
    if (t < TT - 1) {
      k_atth<<<32, 256, 0, stream>>>(htn, h2aWb, h2a_b, ah);
      k_e<<<MM / 4, 256, 0, stream>>>(p_att, ah, alpha_W, alpha_b, eb);
    }
  }
  k_logall<<<600, 256, 0, stream>>>(Xh + (size_t)BB * HH, lWb, logit_b, out);
  k_lsmall<<<TT * BB, 256, 0, stream>>>(out);
}

// Round 16
// 705.824 us; speedup vs baseline: 1.2928x; 1.0896x over previous
//
#include <hip/hip_runtime.h>
#include <stdint.h>
#include <stddef.h>

#define BB 64
#define LL 196
#define FF 2048
#define HH 512
#define VV 9488
#define NPAD 9600        // lWb padded rows; pad rows stay finite poison, never stored
#define TT 16
#define KXX 3072         // H + F + H (x' = [xt, att_res, h])
#define MM (BB * LL)     // 12544

typedef short short8 __attribute__((ext_vector_type(8)));
typedef short short4v __attribute__((ext_vector_type(4)));
typedef float f32x4 __attribute__((ext_vector_type(4)));
typedef unsigned short u16;
typedef unsigned char u8;

typedef __attribute__((address_space(3))) uint32_t lds_u32_t;
typedef __attribute__((address_space(1))) const uint32_t glb_u32_t;

__device__ __forceinline__ u16 f2bf(float f) {
  uint32_t u = __builtin_bit_cast(uint32_t, f);
  u += 0x7FFFu + ((u >> 16) & 1u);   // RNE
  return (u16)(u >> 16);
}
__device__ __forceinline__ float bf2f(u16 s) {
  return __builtin_bit_cast(float, ((uint32_t)s) << 16);
}
__device__ __forceinline__ float fast_tanh(float x) {
  return 1.0f - 2.0f / (1.0f + __expf(2.0f * x));
}
__device__ __forceinline__ float fast_sig(float x) {
  return 1.0f / (1.0f + __expf(-x));
}
__device__ __forceinline__ float wred_sum(float v) {
#pragma unroll
  for (int o = 32; o; o >>= 1) v += __shfl_xor(v, o, 64);
  return v;
}
__device__ __forceinline__ float wred_max(float v) {
#pragma unroll
  for (int o = 32; o; o >>= 1) v = fmaxf(v, __shfl_xor(v, o, 64));
  return v;
}
__device__ __forceinline__ f32x4 mfma16(short8 a, short8 b, f32x4 c) {
  return __builtin_amdgcn_mfma_f32_16x16x32_bf16(a, b, c, 0, 0, 0);
}
__device__ __forceinline__ short8 ldbf(const u16* p) {
  return *reinterpret_cast<const short8*>(p);
}
// async global->LDS, 16B per lane; lds addr must be wave-base + lane*16 (linear)
__device__ __forceinline__ void gload16(const u16* g, u16* l) {
  __builtin_amdgcn_global_load_lds((glb_u32_t*)g, (lds_u32_t*)l, 16, 0, 0);
}

// ---------------- one fused setup kernel (R14 one-shot structure + fp8 pack) ----------------
// regions: ctx[0,1024) lin[1024,2048) h2a[2048,2304) logit[2304,7048)
// fc[7048,7176) attb[7176,32264) wc[32264,38408) xemb[38408,38920)
__global__ __launch_bounds__(256) void k_setup(
    const float* __restrict__ ctx_W, u16* __restrict__ ctxWb,
    const float* __restrict__ lin_W, u16* __restrict__ linWb,
    const float* __restrict__ h2a_W, u16* __restrict__ h2aWb,
    const float* __restrict__ logit_W, u16* __restrict__ lWb,
    const float* __restrict__ fc, u16* __restrict__ fcb,
    const float* __restrict__ attf, u16* __restrict__ attb, u8* __restrict__ att8,
    const float* __restrict__ Wih, const float* __restrict__ Whh, u16* __restrict__ Wc,
    const float* __restrict__ emb, const int* __restrict__ seq, u16* __restrict__ Xemb) {
  int blk = blockIdx.x, t = threadIdx.x;
  if (blk < 32264) {
    const float* s; u16* d; int rel;
    bool isAtt = false;
    if (blk < 1024)      { s = ctx_W;   d = ctxWb; rel = blk; }
    else if (blk < 2048) { s = lin_W;   d = linWb; rel = blk - 1024; }
    else if (blk < 2304) { s = h2a_W;   d = h2aWb; rel = blk - 2048; }
    else if (blk < 7048) { s = logit_W; d = lWb;   rel = blk - 2304; }
    else if (blk < 7176) { s = fc;      d = fcb;   rel = blk - 7048; }
    else                 { s = attf;    d = attb;  rel = blk - 7176; isAtt = true; }
    int i = rel * 256 + t;
    float4 v = reinterpret_cast<const float4*>(s)[i];
    ushort4 o; o.x = f2bf(v.x); o.y = f2bf(v.y); o.z = f2bf(v.z); o.w = f2bf(v.w);
    reinterpret_cast<ushort4*>(d)[i] = o;
    if (isAtt && att8) {
      uint32_t p8 = __builtin_amdgcn_cvt_pk_fp8_f32(v.x, v.y, 0u, false);
      p8 = __builtin_amdgcn_cvt_pk_fp8_f32(v.z, v.w, p8, true);
      reinterpret_cast<uint32_t*>(att8)[i] = p8;
    }
  } else if (blk < 38408) {
    int i = (blk - 32264) * 256 + t;
    int idx = i * 4;
    int n = idx / KXX, k = idx - n * KXX;
    const float* p = (k < 2560) ? (Wih + (size_t)n * 2560 + k) : (Whh + (size_t)n * HH + (k - 2560));
    float4 v = *reinterpret_cast<const float4*>(p);
    ushort4 o; o.x = f2bf(v.x); o.y = f2bf(v.y); o.z = f2bf(v.z); o.w = f2bf(v.w);
    reinterpret_cast<ushort4*>(Wc)[i] = o;
  } else {
    int i = (blk - 38408) * 256 + t;
    int idx = i * 4;
    int tt = idx / (BB * HH);
    int r = idx - tt * (BB * HH);
    int b = r / HH, k = r - b * HH;
    int tok = seq[b * 17 + tt];
    float4 v = *reinterpret_cast<const float4*>(emb + (size_t)tok * HH + k);
    ushort4 o; o.x = f2bf(v.x); o.y = f2bf(v.y); o.z = f2bf(v.z); o.w = f2bf(v.w);
    reinterpret_cast<ushort4*>(Xemb)[i] = o;
  }
}

// h0 = c0 = fc @ lin_W^T + lin_b  (device body; rides on k_patt, uses threads 0..255)
__device__ __forceinline__ void dev_h0(int nt, const u16* __restrict__ fcb, const u16* __restrict__ linWb,
                                       const float* __restrict__ lin_b,
                                       u16* __restrict__ hb, float* __restrict__ c) {
  int lane = threadIdx.x & 63;
  int m0 = (threadIdx.x >> 6) * 16, n0 = nt * 16;
  const u16* xr = fcb + (size_t)(m0 + (lane & 15)) * FF + ((lane >> 4) * 8);
  const u16* wr = linWb + (size_t)(n0 + (lane & 15)) * FF + ((lane >> 4) * 8);
  f32x4 acc = {0.f, 0.f, 0.f, 0.f};
#pragma unroll 8
  for (int kk = 0; kk < 64; ++kk)
    acc = mfma16(ldbf(xr + kk * 32), ldbf(wr + kk * 32), acc);
  int col = n0 + (lane & 15);
  float bias = lin_b[col];
#pragma unroll
  for (int j = 0; j < 4; ++j) {
    int row = m0 + (lane >> 4) * 4 + j;
    float v = acc[j] + bias;
    hb[row * HH + col] = f2bf(v);
    c[row * HH + col] = v;
  }
}

// p_att = att_feats @ ctx_W^T + ctx_b. 128x128 tile, 8 waves/block (R14-proven);
// XCD remap; gload_lds staging. Blocks 392..423: h0 rider.
__global__ __launch_bounds__(512) void k_patt(const u16* __restrict__ attb,
                                              const u16* __restrict__ ctxWb, const float* __restrict__ ctx_b,
                                              u16* __restrict__ p_att,
                                              const u16* __restrict__ fcb, const u16* __restrict__ linWb,
                                              const float* __restrict__ lin_b,
                                              u16* __restrict__ hb0, float* __restrict__ c) {
  __shared__ __align__(16) u16 As[128][32];
  __shared__ __align__(16) u16 Bs[128][32];
  int d = blockIdx.x;
  if (d >= 392) {                        // h0 rider (MFMA only, no barriers)
    if (threadIdx.x < 256) dev_h0(d - 392, fcb, linWb, lin_b, hb0, c);
    return;
  }
  int bid = (d & 7) * 49 + (d >> 3);     // 392 = 8*49, bijective XCD remap
  int mb = bid >> 2, nb = bid & 3;       // 98 x 4
  int m0 = mb * 128, n0 = nb * 128;
  int tid = threadIdx.x;                 // 0..511
  int wid = tid >> 6, lane = tid & 63;
  int wr2 = wid >> 2, wc2 = wid & 3;     // 2 row-halves x 4 col-quadrants
  int ar = lane & 15, ak = (lane >> 4) * 8;
  const u16* ga = attb + (size_t)(m0 + (tid >> 2)) * FF + (tid & 3) * 8;
  const u16* gb = ctxWb + (size_t)(n0 + (tid >> 2)) * FF + (tid & 3) * 8;
  u16* la = &As[0][0] + tid * 8;
  u16* lb = &Bs[0][0] + tid * 8;

  f32x4 zero = {0.f, 0.f, 0.f, 0.f};
  f32x4 acc[4][2];
#pragma unroll
  for (int i = 0; i < 4; ++i)
#pragma unroll
    for (int j = 0; j < 2; ++j) acc[i][j] = zero;

  for (int ks = 0; ks < 64; ++ks) {
    int k0 = ks * 32;
    __syncthreads();
    gload16(ga + k0, la);
    gload16(gb + k0, lb);
    __syncthreads();
    short8 af[4], bfr[2];
#pragma unroll
    for (int i = 0; i < 4; ++i)
      af[i] = *reinterpret_cast<const short8*>(&As[wr2 * 64 + i * 16 + ar][ak]);
#pragma unroll
    for (int j = 0; j < 2; ++j)
      bfr[j] = *reinterpret_cast<const short8*>(&Bs[wc2 * 32 + j * 16 + ar][ak]);
#pragma unroll
    for (int i = 0; i < 4; ++i)
#pragma unroll
      for (int j = 0; j < 2; ++j)
        acc[i][j] = mfma16(af[i], bfr[j], acc[i][j]);
  }
#pragma unroll
  for (int j = 0; j < 2; ++j) {
    int col = n0 + wc2 * 32 + j * 16 + ar;
    float bias = ctx_b[col];
#pragma unroll
    for (int i = 0; i < 4; ++i)
#pragma unroll
      for (int q = 0; q < 4; ++q) {
        int row = m0 + wr2 * 64 + i * 16 + (lane >> 4) * 4 + q;
        p_att[(size_t)row * HH + col] = f2bf(acc[i][j][q] + bias);
      }
  }
}

// ---------------- per-step device bodies (proven) ----------------
__device__ __forceinline__ void dev_atth(int nt, const u16* __restrict__ hb, const u16* __restrict__ h2aWb,
                                         const float* __restrict__ h2ab, float* __restrict__ ah) {
  int lane = threadIdx.x & 63;
  int m0 = (threadIdx.x >> 6) * 16, n0 = nt * 16;
  int ak = (lane >> 4) * 8;
  const u16* xr = hb + (size_t)(m0 + (lane & 15)) * HH + ak;
  const u16* wr = h2aWb + (size_t)(n0 + (lane & 15)) * HH + ak;
  f32x4 acc = {0.f, 0.f, 0.f, 0.f};
#pragma unroll
  for (int kk = 0; kk < 16; ++kk)
    acc = mfma16(ldbf(xr + kk * 32), ldbf(wr + kk * 32), acc);
  int col = n0 + (lane & 15);
  float bias = h2ab[col];
#pragma unroll
  for (int j = 0; j < 4; ++j)
    ah[(size_t)(m0 + (lane >> 4) * 4 + j) * HH + col] = acc[j] + bias;
}

__device__ __forceinline__ void dev_e(int bid4, const u16* __restrict__ p_att, const float* __restrict__ ah,
                                      const float* __restrict__ alphaW, const float* __restrict__ alphab,
                                      float* __restrict__ e) {
  int gw = bid4 * 4 + (threadIdx.x >> 6);   // [0, 12544)
  int lane = threadIdx.x & 63;
  int b = gw / LL, l = gw - b * LL;
  short8 pa = ldbf(p_att + (size_t)gw * HH + lane * 8);
  const float4* ap = reinterpret_cast<const float4*>(ah + (size_t)b * HH + lane * 8);
  float4 a0 = ap[0], a1 = ap[1];
  const float4* wp = reinterpret_cast<const float4*>(alphaW + lane * 8);
  float4 w0 = wp[0], w1 = wp[1];
  float s = fast_tanh(bf2f((u16)pa[0]) + a0.x) * w0.x
          + fast_tanh(bf2f((u16)pa[1]) + a0.y) * w0.y
          + fast_tanh(bf2f((u16)pa[2]) + a0.z) * w0.z
          + fast_tanh(bf2f((u16)pa[3]) + a0.w) * w0.w
          + fast_tanh(bf2f((u16)pa[4]) + a1.x) * w1.x
          + fast_tanh(bf2f((u16)pa[5]) + a1.y) * w1.y
          + fast_tanh(bf2f((u16)pa[6]) + a1.z) * w1.z
          + fast_tanh(bf2f((u16)pa[7]) + a1.w) * w1.w;
  s = wred_sum(s);
  if (!lane) e[b * 256 + l] = s + alphab[0];
}

// ---------------- per-step kernels (4 per step, logits deferred) ----------------
__global__ __launch_bounds__(256) void k_atth(const u16* __restrict__ hb, const u16* __restrict__ h2aWb,
                                              const float* __restrict__ h2ab, float* __restrict__ ah) {
  dev_atth(blockIdx.x, hb, h2aWb, h2ab, ah);
}
__global__ __launch_bounds__(256) void k_e(const u16* __restrict__ p_att, const float* __restrict__ ah,
                                           const float* __restrict__ alphaW, const float* __restrict__ alphab,
                                           float* __restrict__ e) {
  dev_e(blockIdx.x, p_att, ah, alphaW, alphab, e);
}

// attR: softmax(e[b,:]) per block (redundant x8, cheap) then weighted sum.
// 512 blocks = b(64) x f-chunk(8) of 256 feats; FP8 halves fabric bytes.
template<bool FP8>
__global__ __launch_bounds__(256) void k_attR(const float* __restrict__ e, const u16* __restrict__ attb,
                                              const u8* __restrict__ att8, u16* __restrict__ xatt) {
  __shared__ float w_s[LL];
  __shared__ float red[8];
  __shared__ float part[4][256];
  int b = blockIdx.x >> 3, f8 = blockIdx.x & 7;
  int t = threadIdx.x, wid = t >> 6, lane = t & 63;
  float ev = (t < LL) ? e[b * 256 + t] : -1e30f;
  float m = wred_max(ev);
  if (!lane) red[wid] = m;
  __syncthreads();
  m = fmaxf(fmaxf(red[0], red[1]), fmaxf(red[2], red[3]));
  float ex = __expf(ev - m);
  float s = wred_sum(ex);
  if (!lane) red[4 + wid] = s;
  __syncthreads();
  s = red[4] + red[5] + red[6] + red[7];
  if (t < LL) w_s[t] = ex / s;
  __syncthreads();

  int f0 = f8 * 256 + lane * 4;
  float a0 = 0.f, a1 = 0.f, a2 = 0.f, a3 = 0.f;
  int l0 = wid * 49;
  if (FP8) {
    const u8* ap = att8 + ((size_t)(b * LL + l0)) * FF + f0;
#pragma unroll 7
    for (int l = 0; l < 49; ++l) {
      float wv = w_s[l0 + l];
      uint32_t pv = *reinterpret_cast<const uint32_t*>(ap);
      ap += FF;
      a0 += wv * __builtin_amdgcn_cvt_f32_fp8(pv, 0);
      a1 += wv * __builtin_amdgcn_cvt_f32_fp8(pv, 1);
      a2 += wv * __builtin_amdgcn_cvt_f32_fp8(pv, 2);
      a3 += wv * __builtin_amdgcn_cvt_f32_fp8(pv, 3);
    }
  } else {
    const u16* ap = attb + ((size_t)(b * LL + l0)) * FF + f0;
#pragma unroll 7
    for (int l = 0; l < 49; ++l) {
      float wv = w_s[l0 + l];
      short4v av = *reinterpret_cast<const short4v*>(ap);
      ap += FF;
      a0 += wv * bf2f((u16)av[0]); a1 += wv * bf2f((u16)av[1]);
      a2 += wv * bf2f((u16)av[2]); a3 += wv * bf2f((u16)av[3]);
    }
  }
  *reinterpret_cast<float4*>(&part[wid][lane * 4]) = make_float4(a0, a1, a2, a3);
  __syncthreads();
  float v = part[0][t] + part[1][t] + part[2][t] + part[3][t];
  xatt[(size_t)b * FF + f8 * 256 + t] = f2bf(v);
}

// gates+LSTM: 128 blocks; XCD-dedup remap (R15-proven win).
__global__ __launch_bounds__(256) void k_gatelstm(const u16* __restrict__ Xemb, const u16* __restrict__ xatt,
                                                  const u16* __restrict__ hb_in, const u16* __restrict__ Wc,
                                                  float* __restrict__ c, u16* __restrict__ hb_out, int tstep) {
  __shared__ float sm[4][4][16][16];
  int d = blockIdx.x;
  int bid = (d & 7) * 16 + (d >> 3);     // bijective: XCD x hosts jt in [x*4, x*4+4)
  int jt = bid >> 2, mq = bid & 3;
  int m0 = mq * 16;
  int lane = threadIdx.x & 63, kq = threadIdx.x >> 6;
  int ar = lane & 15, ak8 = (lane >> 4) * 8;
  int m = m0 + ar;
  int wn = jt * 16 + ar;
  f32x4 zero = {0.f, 0.f, 0.f, 0.f};
  f32x4 acc[4] = {zero, zero, zero, zero};
  const u16* xr0 = Xemb + ((size_t)tstep * BB + m) * HH;
  const u16* xr1 = xatt + (size_t)m * FF;
  const u16* xr2 = hb_in + (size_t)m * HH;

#pragma unroll 4
  for (int kk = 0; kk < 24; ++kk) {
    int k = kq * 768 + kk * 32 + ak8;
    short8 a;
    if (k < 512)       a = ldbf(xr0 + k);
    else if (k < 2560) a = ldbf(xr1 + (k - 512));
    else               a = ldbf(xr2 + (k - 2560));
    short8 bv[4];
#pragma unroll
    for (int g = 0; g < 4; ++g)
      bv[g] = ldbf(Wc + (size_t)(g * 512 + wn) * KXX + k);
#pragma unroll
    for (int g = 0; g < 4; ++g) acc[g] = mfma16(a, bv[g], acc[g]);
  }
#pragma unroll
  for (int g = 0; g < 4; ++g)
#pragma unroll
    for (int q = 0; q < 4; ++q)
      sm[kq][g][(lane >> 4) * 4 + q][ar] = acc[g][q];
  __syncthreads();
  int r = threadIdx.x >> 4, cc = threadIdx.x & 15;
  float gi = sm[0][0][r][cc] + sm[1][0][r][cc] + sm[2][0][r][cc] + sm[3][0][r][cc];
  float gf = sm[0][1][r][cc] + sm[1][1][r][cc] + sm[2][1][r][cc] + sm[3][1][r][cc];
  float gg = sm[0][2][r][cc] + sm[1][2][r][cc] + sm[2][2][r][cc] + sm[3][2][r][cc];
  float go = sm[0][3][r][cc] + sm[1][3][r][cc] + sm[2][3][r][cc] + sm[3][3][r][cc];
  int idx = (m0 + r) * HH + jt * 16 + cc;
  float cn = fast_sig(gf) * c[idx] + fast_sig(gi) * fast_tanh(gg);
  float hn = fast_sig(go) * fast_tanh(cn);
  c[idx] = cn;
  hb_out[idx] = f2bf(hn);
}

// ---------------- deferred logits (writes straight into d_out; proven) ----------------
__global__ __launch_bounds__(256) void k_logall(const u16* __restrict__ XhL, const u16* __restrict__ lWb,
                                                const float* __restrict__ lb, float* __restrict__ out) {
  __shared__ __align__(16) u16 As[128][32];
  __shared__ __align__(16) u16 Bs[128][32];
  int d = blockIdx.x;
  int mb = d & 7, nb = d >> 3;
  int m0 = mb * 128, n0 = nb * 128;
  int tid = threadIdx.x;
  int wid = tid >> 6, lane = tid & 63;
  int wr = wid >> 1, wc = wid & 1;
  int ar = lane & 15, ak = (lane >> 4) * 8;
  int rt = tid >> 1, st = tid & 1;
  const u16* agp = XhL + (size_t)(m0 + rt) * HH + st * 16;
  const u16* bgp = lWb + (size_t)(n0 + rt) * HH + st * 16;

  f32x4 zero = {0.f, 0.f, 0.f, 0.f};
  f32x4 acc[4][4];
#pragma unroll
  for (int i = 0; i < 4; ++i)
#pragma unroll
    for (int j = 0; j < 4; ++j) acc[i][j] = zero;

  for (int ks = 0; ks < 16; ++ks) {
    int k0 = ks * 32;
    short8 a0 = ldbf(agp + k0);
    short8 a1 = ldbf(agp + k0 + 8);
    short8 b0 = ldbf(bgp + k0);
    short8 b1 = ldbf(bgp + k0 + 8);
    __syncthreads();
    *reinterpret_cast<short8*>(&As[rt][st * 16]) = a0;
    *reinterpret_cast<short8*>(&As[rt][st * 16 + 8]) = a1;
    *reinterpret_cast<short8*>(&Bs[rt][st * 16]) = b0;
    *reinterpret_cast<short8*>(&Bs[rt][st * 16 + 8]) = b1;
    __syncthreads();
    short8 af[4], bfr[4];
#pragma unroll
    for (int i = 0; i < 4; ++i)
      af[i] = *reinterpret_cast<const short8*>(&As[wr * 64 + i * 16 + ar][ak]);
#pragma unroll
    for (int j = 0; j < 4; ++j)
      bfr[j] = *reinterpret_cast<const short8*>(&Bs[wc * 64 + j * 16 + ar][ak]);
#pragma unroll
    for (int i = 0; i < 4; ++i)
#pragma unroll
      for (int j = 0; j < 4; ++j)
        acc[i][j] = mfma16(af[i], bfr[j], acc[i][j]);
  }
#pragma unroll
  for (int j = 0; j < 4; ++j) {
    int col = n0 + wc * 64 + j * 16 + ar;
    if (col >= VV) continue;
    float bias = lb[col];
#pragma unroll
    for (int i = 0; i < 4; ++i)
#pragma unroll
      for (int q = 0; q < 4; ++q) {
        int row = m0 + wr * 64 + i * 16 + (lane >> 4) * 4 + q;
        int bb = row & 63, ts = row >> 6;
        out[((size_t)(bb * TT + ts)) * VV + col] = acc[i][j][q] + bias;
      }
  }
}

// in-place log-softmax on all 1024 out rows (proven)
__global__ __launch_bounds__(256) void k_lsmall(float* __restrict__ out) {
  __shared__ float red[8];
  float* row = out + (size_t)blockIdx.x * VV;
  float4* row4 = reinterpret_cast<float4*>(row);
  int t = threadIdx.x, wid = t >> 6, lane = t & 63;
  float4 v[10];
  float m = -1e30f;
#pragma unroll
  for (int p = 0; p < 10; ++p) {
    int i4 = p * 256 + t;
    if (i4 < VV / 4) {
      v[p] = row4[i4];
      m = fmaxf(m, fmaxf(fmaxf(v[p].x, v[p].y), fmaxf(v[p].z, v[p].w)));
    } else {
      v[p] = make_float4(-1e30f, -1e30f, -1e30f, -1e30f);
    }
  }
  m = wred_max(m);
  if (!lane) red[wid] = m;
  __syncthreads();
  m = fmaxf(fmaxf(red[0], red[1]), fmaxf(red[2], red[3]));
  float s = 0.f;
#pragma unroll
  for (int p = 0; p < 10; ++p)
    s += __expf(v[p].x - m) + __expf(v[p].y - m) + __expf(v[p].z - m) + __expf(v[p].w - m);
  s = wred_sum(s);
  if (!lane) red[4 + wid] = s;
  __syncthreads();
  s = red[4] + red[5] + red[6] + red[7];
  float lse = m + __logf(s);
#pragma unroll
  for (int p = 0; p < 10; ++p) {
    int i4 = p * 256 + t;
    if (i4 < VV / 4)
      row4[i4] = make_float4(v[p].x - lse, v[p].y - lse, v[p].z - lse, v[p].w - lse);
  }
}

// ---------------- host ----------------
extern "C" void kernel_launch(void* const* d_in, const int* in_sizes, int n_in,
                              void* d_out, int out_size, void* d_ws, size_t ws_size,
                              hipStream_t stream) {
  const float* fc      = (const float*)d_in[0];
  const float* attf    = (const float*)d_in[1];
  const int*   seq     = (const int*)d_in[2];
  const float* lin_W   = (const float*)d_in[3];
  const float* lin_b   = (const float*)d_in[4];
  const float* emb     = (const float*)d_in[5];
  const float* Wih     = (const float*)d_in[6];
  const float* Whh     = (const float*)d_in[7];
  const float* ctx_W   = (const float*)d_in[8];
  const float* ctx_b   = (const float*)d_in[9];
  const float* h2a_W   = (const float*)d_in[10];
  const float* h2a_b   = (const float*)d_in[11];
  const float* alpha_W = (const float*)d_in[12];
  const float* alpha_b = (const float*)d_in[13];
  const float* logit_W = (const float*)d_in[14];
  const float* logit_b = (const float*)d_in[15];
  float* out = (float*)d_out;

  char* base = (char*)d_ws;
  size_t off = 0;
  auto alloc = [&](size_t bytes) -> char* {
    off = (off + 255) & ~(size_t)255;
    char* p = base + off;
    off += bytes;
    return p;
  };
  // base footprint ~90.3 MiB; att8 +24.5 MiB (R12 proved ws covers ~117 MiB)
  u16*   p_att  = (u16*)alloc((size_t)MM * HH * 2);
  u16*   ctxWb  = (u16*)alloc((size_t)HH * FF * 2);
  u16*   linWb  = (u16*)alloc((size_t)HH * FF * 2);
  u16*   fcb    = (u16*)alloc((size_t)BB * FF * 2);
  u16*   h2aWb  = (u16*)alloc((size_t)HH * HH * 2);
  u16*   Xemb   = (u16*)alloc((size_t)TT * BB * HH * 2);
  float* c      = (float*)alloc((size_t)BB * HH * 4);
  u16*   Xh     = (u16*)alloc((size_t)(TT + 1) * BB * HH * 2);   // slice 0 = h0
  u16*   xatt   = (u16*)alloc((size_t)BB * FF * 2);
  float* eb     = (float*)alloc((size_t)BB * 256 * 4);
  float* ah     = (float*)alloc((size_t)BB * HH * 4);
  u16*   Wc     = (u16*)alloc((size_t)2048 * KXX * 2);
  u16*   lWb    = (u16*)alloc((size_t)NPAD * HH * 2);   // pad rows: finite poison, never stored
  u16*   attb   = (u16*)alloc((size_t)MM * FF * 2);
  bool useF8 = (((off + 255) & ~(size_t)255) + (size_t)MM * FF) <= ws_size;
  u8* att8 = useF8 ? (u8*)alloc((size_t)MM * FF) : nullptr;

  k_setup<<<38920, 256, 0, stream>>>(ctx_W, ctxWb, lin_W, linWb, h2a_W, h2aWb, logit_W, lWb,
                                     fc, fcb, attf, attb, att8, Wih, Whh, Wc, emb, seq, Xemb);
  // p_att GEMM + h0 rider
  k_patt<<<424, 512, 0, stream>>>(attb, ctxWb, ctx_b, p_att, fcb, linWb, lin_b, Xh, c);

  // prologue: ah(0), e(0)
  k_atth<<<32, 256, 0, stream>>>(Xh, h2aWb, h2a_b, ah);
  k_e<<<MM / 4, 256, 0, stream>>>(p_att, ah, alpha_W, alpha_b, eb);

  for (int t = 0; t < TT; ++t) {
    u16* ht  = Xh + (size_t)t * BB * HH;
    u16* htn = Xh + (size_t)(t + 1) * BB * HH;
    if (useF8) k_attR<true><<<512, 256, 0, stream>>>(eb, attb, att8, xatt);
    else       k_attR<false><<<512, 256, 0, stream>>>(eb, attb, att8, xatt);
    k_gatelstm<<<128, 256, 0, stream>>>(Xemb, xatt, ht, Wc, c, htn, t);
    if (t < TT - 1) {
      k_atth<<<32, 256, 0, stream>>>(htn, h2aWb, h2a_b, ah);
      k_e<<<MM / 4, 256, 0, stream>>>(p_att, ah, alpha_W, alpha_b, eb);
    }
  }
  k_logall<<<600, 256, 0, stream>>>(Xh + (size_t)BB * HH, lWb, logit_b, out);
  k_lsmall<<<TT * BB, 256, 0, stream>>>(out);
}

// Round 17
// 700.618 us; speedup vs baseline: 1.3024x; 1.0074x over previous
//
#include <hip/hip_runtime.h>
#include <stdint.h>
#include <stddef.h>

#define BB 64
#define LL 196
#define FF 2048
#define HH 512
#define VV 9488
#define NPAD 9600        // lWb padded rows; pad rows stay finite poison, never stored
#define TT 16
#define KXX 3072         // H + F + H (x' = [xt, att_res, h])
#define MM (BB * LL)     // 12544

typedef short short8 __attribute__((ext_vector_type(8)));
typedef short short4v __attribute__((ext_vector_type(4)));
typedef float f32x4 __attribute__((ext_vector_type(4)));
typedef unsigned short u16;
typedef unsigned char u8;
typedef unsigned long long u64;

typedef __attribute__((address_space(3))) uint32_t lds_u32_t;
typedef __attribute__((address_space(1))) const uint32_t glb_u32_t;

__device__ __forceinline__ u16 f2bf(float f) {
  uint32_t u = __builtin_bit_cast(uint32_t, f);
  u += 0x7FFFu + ((u >> 16) & 1u);   // RNE
  return (u16)(u >> 16);
}
__device__ __forceinline__ float bf2f(u16 s) {
  return __builtin_bit_cast(float, ((uint32_t)s) << 16);
}
__device__ __forceinline__ float fast_tanh(float x) {
  return 1.0f - 2.0f / (1.0f + __expf(2.0f * x));
}
__device__ __forceinline__ float fast_sig(float x) {
  return 1.0f / (1.0f + __expf(-x));
}
__device__ __forceinline__ float wred_sum(float v) {
#pragma unroll
  for (int o = 32; o; o >>= 1) v += __shfl_xor(v, o, 64);
  return v;
}
__device__ __forceinline__ float wred_max(float v) {
#pragma unroll
  for (int o = 32; o; o >>= 1) v = fmaxf(v, __shfl_xor(v, o, 64));
  return v;
}
__device__ __forceinline__ f32x4 mfma16(short8 a, short8 b, f32x4 c) {
  return __builtin_amdgcn_mfma_f32_16x16x32_bf16(a, b, c, 0, 0, 0);
}
__device__ __forceinline__ f32x4 mfma8(u64 a, u64 b, f32x4 c) {
  return __builtin_amdgcn_mfma_f32_16x16x32_fp8_fp8((long long)a, (long long)b, c, 0, 0, 0);
}
__device__ __forceinline__ short8 ldbf(const u16* p) {
  return *reinterpret_cast<const short8*>(p);
}
__device__ __forceinline__ u8 f2fp8(float v) {
  return (u8)(__builtin_amdgcn_cvt_pk_fp8_f32(v, v, 0u, false) & 0xFFu);
}
// async global->LDS, 16B per lane; lds addr must be wave-base + lane*16 (linear)
__device__ __forceinline__ void gload16(const void* g, void* l) {
  __builtin_amdgcn_global_load_lds((glb_u32_t*)g, (lds_u32_t*)l, 16, 0, 0);
}

// ---------------- one fused setup kernel ----------------
// regions: ctx->fp8[0,1024) lin[1024,2048) h2a[2048,2304) logit[2304,7048)
// fc[7048,7176) attf->fp8[7176,32264) wc[32264,38408) xemb[38408,38920)
__global__ __launch_bounds__(256) void k_setup(
    const float* __restrict__ ctx_W, u8* __restrict__ ctxW8,
    const float* __restrict__ lin_W, u16* __restrict__ linWb,
    const float* __restrict__ h2a_W, u16* __restrict__ h2aWb,
    const float* __restrict__ logit_W, u16* __restrict__ lWb,
    const float* __restrict__ fc, u16* __restrict__ fcb,
    const float* __restrict__ attf, u8* __restrict__ att8,
    const float* __restrict__ Wih, const float* __restrict__ Whh, u16* __restrict__ Wc,
    const float* __restrict__ emb, const int* __restrict__ seq, u16* __restrict__ Xemb) {
  int blk = blockIdx.x, t = threadIdx.x;
  if (blk < 1024) {                       // ctx_W -> fp8
    int i = blk * 256 + t;
    float4 v = reinterpret_cast<const float4*>(ctx_W)[i];
    uint32_t p8 = __builtin_amdgcn_cvt_pk_fp8_f32(v.x, v.y, 0u, false);
    p8 = __builtin_amdgcn_cvt_pk_fp8_f32(v.z, v.w, p8, true);
    reinterpret_cast<uint32_t*>(ctxW8)[i] = p8;
  } else if (blk < 7176) {                // bf16 regions
    const float* s; u16* d; int rel;
    if (blk < 2048)      { s = lin_W;   d = linWb; rel = blk - 1024; }
    else if (blk < 2304) { s = h2a_W;   d = h2aWb; rel = blk - 2048; }
    else if (blk < 7048) { s = logit_W; d = lWb;   rel = blk - 2304; }
    else                 { s = fc;      d = fcb;   rel = blk - 7048; }
    int i = rel * 256 + t;
    float4 v = reinterpret_cast<const float4*>(s)[i];
    ushort4 o; o.x = f2bf(v.x); o.y = f2bf(v.y); o.z = f2bf(v.z); o.w = f2bf(v.w);
    reinterpret_cast<ushort4*>(d)[i] = o;
  } else if (blk < 32264) {               // att_feats -> fp8 only
    int i = (blk - 7176) * 256 + t;
    float4 v = reinterpret_cast<const float4*>(attf)[i];
    uint32_t p8 = __builtin_amdgcn_cvt_pk_fp8_f32(v.x, v.y, 0u, false);
    p8 = __builtin_amdgcn_cvt_pk_fp8_f32(v.z, v.w, p8, true);
    reinterpret_cast<uint32_t*>(att8)[i] = p8;
  } else if (blk < 38408) {
    int i = (blk - 32264) * 256 + t;
    int idx = i * 4;
    int n = idx / KXX, k = idx - n * KXX;
    const float* p = (k < 2560) ? (Wih + (size_t)n * 2560 + k) : (Whh + (size_t)n * HH + (k - 2560));
    float4 v = *reinterpret_cast<const float4*>(p);
    ushort4 o; o.x = f2bf(v.x); o.y = f2bf(v.y); o.z = f2bf(v.z); o.w = f2bf(v.w);
    reinterpret_cast<ushort4*>(Wc)[i] = o;
  } else {
    int i = (blk - 38408) * 256 + t;
    int idx = i * 4;
    int tt = idx / (BB * HH);
    int r = idx - tt * (BB * HH);
    int b = r / HH, k = r - b * HH;
    int tok = seq[b * 17 + tt];
    float4 v = *reinterpret_cast<const float4*>(emb + (size_t)tok * HH + k);
    ushort4 o; o.x = f2bf(v.x); o.y = f2bf(v.y); o.z = f2bf(v.z); o.w = f2bf(v.w);
    reinterpret_cast<ushort4*>(Xemb)[i] = o;
  }
}

// h0 = c0 = fc @ lin_W^T + lin_b  (bf16 MFMA; rides on k_patt, threads 0..255)
__device__ __forceinline__ void dev_h0(int nt, const u16* __restrict__ fcb, const u16* __restrict__ linWb,
                                       const float* __restrict__ lin_b,
                                       u16* __restrict__ hb, float* __restrict__ c) {
  int lane = threadIdx.x & 63;
  int m0 = (threadIdx.x >> 6) * 16, n0 = nt * 16;
  const u16* xr = fcb + (size_t)(m0 + (lane & 15)) * FF + ((lane >> 4) * 8);
  const u16* wr = linWb + (size_t)(n0 + (lane & 15)) * FF + ((lane >> 4) * 8);
  f32x4 acc = {0.f, 0.f, 0.f, 0.f};
#pragma unroll 8
  for (int kk = 0; kk < 64; ++kk)
    acc = mfma16(ldbf(xr + kk * 32), ldbf(wr + kk * 32), acc);
  int col = n0 + (lane & 15);
  float bias = lin_b[col];
#pragma unroll
  for (int j = 0; j < 4; ++j) {
    int row = m0 + (lane >> 4) * 4 + j;
    float v = acc[j] + bias;
    hb[row * HH + col] = f2bf(v);
    c[row * HH + col] = v;
  }
}

// p_att = att_feats @ ctx_W^T + ctx_b, FP8 x FP8 MFMA, fp8 output.
// 128x128 tile, 8 waves/block; XCD remap; gload_lds staging (1 load/thread/K-step:
// threads 0..255 stage the 4KB A slab, 256..511 the B slab). h0 rider at 392..423.
__global__ __launch_bounds__(512) void k_patt(const u8* __restrict__ att8,
                                              const u8* __restrict__ ctxW8, const float* __restrict__ ctx_b,
                                              u8* __restrict__ p_att8,
                                              const u16* __restrict__ fcb, const u16* __restrict__ linWb,
                                              const float* __restrict__ lin_b,
                                              u16* __restrict__ hb0, float* __restrict__ c) {
  __shared__ __align__(16) u8 As[128][32];
  __shared__ __align__(16) u8 Bs[128][32];
  int d = blockIdx.x;
  if (d >= 392) {                        // h0 rider
    if (threadIdx.x < 256) dev_h0(d - 392, fcb, linWb, lin_b, hb0, c);
    return;
  }
  int bid = (d & 7) * 49 + (d >> 3);     // 392 = 8*49, bijective XCD remap
  int mb = bid >> 2, nb = bid & 3;       // 98 x 4
  int m0 = mb * 128, n0 = nb * 128;
  int tid = threadIdx.x;                 // 0..511
  int wid = tid >> 6, lane = tid & 63;
  int wr2 = wid >> 2, wc2 = wid & 3;     // 2 row-halves x 4 col-quadrants
  int ar = lane & 15;
  int akb = (lane >> 4) * 8;             // byte offset of 8-elem fp8 fragment
  bool isA = tid < 256;
  int t2 = tid & 255;
  const u8* gsrc = isA ? (att8 + (size_t)(m0 + (t2 >> 1)) * FF + (t2 & 1) * 16)
                       : (ctxW8 + (size_t)(n0 + (t2 >> 1)) * FF + (t2 & 1) * 16);
  u8* ldst = isA ? (&As[0][0] + t2 * 16) : (&Bs[0][0] + t2 * 16);

  f32x4 zero = {0.f, 0.f, 0.f, 0.f};
  f32x4 acc[4][2];
#pragma unroll
  for (int i = 0; i < 4; ++i)
#pragma unroll
    for (int j = 0; j < 2; ++j) acc[i][j] = zero;

  for (int ks = 0; ks < 64; ++ks) {
    int k0 = ks * 32;
    __syncthreads();
    gload16(gsrc + k0, ldst);
    __syncthreads();
    u64 af[4], bfr[2];
#pragma unroll
    for (int i = 0; i < 4; ++i)
      af[i] = *reinterpret_cast<const u64*>(&As[wr2 * 64 + i * 16 + ar][akb]);
#pragma unroll
    for (int j = 0; j < 2; ++j)
      bfr[j] = *reinterpret_cast<const u64*>(&Bs[wc2 * 32 + j * 16 + ar][akb]);
#pragma unroll
    for (int i = 0; i < 4; ++i)
#pragma unroll
      for (int j = 0; j < 2; ++j)
        acc[i][j] = mfma8(af[i], bfr[j], acc[i][j]);
  }
#pragma unroll
  for (int j = 0; j < 2; ++j) {
    int col = n0 + wc2 * 32 + j * 16 + ar;
    float bias = ctx_b[col];
#pragma unroll
    for (int i = 0; i < 4; ++i)
#pragma unroll
      for (int q = 0; q < 4; ++q) {
        int row = m0 + wr2 * 64 + i * 16 + (lane >> 4) * 4 + q;
        p_att8[(size_t)row * HH + col] = f2fp8(acc[i][j][q] + bias);
      }
  }
}

// ---------------- per-step device bodies ----------------
__device__ __forceinline__ void dev_atth(int nt, const u16* __restrict__ hb, const u16* __restrict__ h2aWb,
                                         const float* __restrict__ h2ab, float* __restrict__ ah) {
  int lane = threadIdx.x & 63;
  int m0 = (threadIdx.x >> 6) * 16, n0 = nt * 16;
  int ak = (lane >> 4) * 8;
  const u16* xr = hb + (size_t)(m0 + (lane & 15)) * HH + ak;
  const u16* wr = h2aWb + (size_t)(n0 + (lane & 15)) * HH + ak;
  f32x4 acc = {0.f, 0.f, 0.f, 0.f};
#pragma unroll
  for (int kk = 0; kk < 16; ++kk)
    acc = mfma16(ldbf(xr + kk * 32), ldbf(wr + kk * 32), acc);
  int col = n0 + (lane & 15);
  float bias = h2ab[col];
#pragma unroll
  for (int j = 0; j < 4; ++j)
    ah[(size_t)(m0 + (lane >> 4) * 4 + j) * HH + col] = acc[j] + bias;
}

// e[b,l] from fp8 p_att (6.4MB/step)
__device__ __forceinline__ void dev_e(int bid4, const u8* __restrict__ p_att8, const float* __restrict__ ah,
                                      const float* __restrict__ alphaW, const float* __restrict__ alphab,
                                      float* __restrict__ e) {
  int gw = bid4 * 4 + (threadIdx.x >> 6);   // [0, 12544)
  int lane = threadIdx.x & 63;
  int b = gw / LL, l = gw - b * LL;
  u64 pv = *reinterpret_cast<const u64*>(p_att8 + (size_t)gw * HH + lane * 8);
  uint32_t lo = (uint32_t)pv, hi = (uint32_t)(pv >> 32);
  float p0 = __builtin_amdgcn_cvt_f32_fp8(lo, 0);
  float p1 = __builtin_amdgcn_cvt_f32_fp8(lo, 1);
  float p2 = __builtin_amdgcn_cvt_f32_fp8(lo, 2);
  float p3 = __builtin_amdgcn_cvt_f32_fp8(lo, 3);
  float p4 = __builtin_amdgcn_cvt_f32_fp8(hi, 0);
  float p5 = __builtin_amdgcn_cvt_f32_fp8(hi, 1);
  float p6 = __builtin_amdgcn_cvt_f32_fp8(hi, 2);
  float p7 = __builtin_amdgcn_cvt_f32_fp8(hi, 3);
  const float4* ap = reinterpret_cast<const float4*>(ah + (size_t)b * HH + lane * 8);
  float4 a0 = ap[0], a1 = ap[1];
  const float4* wp = reinterpret_cast<const float4*>(alphaW + lane * 8);
  float4 w0 = wp[0], w1 = wp[1];
  float s = fast_tanh(p0 + a0.x) * w0.x
          + fast_tanh(p1 + a0.y) * w0.y
          + fast_tanh(p2 + a0.z) * w0.z
          + fast_tanh(p3 + a0.w) * w0.w
          + fast_tanh(p4 + a1.x) * w1.x
          + fast_tanh(p5 + a1.y) * w1.y
          + fast_tanh(p6 + a1.z) * w1.z
          + fast_tanh(p7 + a1.w) * w1.w;
  s = wred_sum(s);
  if (!lane) e[b * 256 + l] = s + alphab[0];
}

// ---------------- per-step kernels (4 per step, logits deferred) ----------------
__global__ __launch_bounds__(256) void k_atth(const u16* __restrict__ hb, const u16* __restrict__ h2aWb,
                                              const float* __restrict__ h2ab, float* __restrict__ ah) {
  dev_atth(blockIdx.x, hb, h2aWb, h2ab, ah);
}
__global__ __launch_bounds__(256) void k_e(const u8* __restrict__ p_att8, const float* __restrict__ ah,
                                           const float* __restrict__ alphaW, const float* __restrict__ alphab,
                                           float* __restrict__ e) {
  dev_e(blockIdx.x, p_att8, ah, alphaW, alphab, e);
}

// attR: softmax(e[b,:]) per block (redundant x8, cheap) then weighted sum (fp8, R16-proven).
// 512 blocks = b(64) x f-chunk(8) of 256 feats.
__global__ __launch_bounds__(256) void k_attR(const float* __restrict__ e, const u8* __restrict__ att8,
                                              u16* __restrict__ xatt) {
  __shared__ float w_s[LL];
  __shared__ float red[8];
  __shared__ float part[4][256];
  int b = blockIdx.x >> 3, f8 = blockIdx.x & 7;
  int t = threadIdx.x, wid = t >> 6, lane = t & 63;
  float ev = (t < LL) ? e[b * 256 + t] : -1e30f;
  float m = wred_max(ev);
  if (!lane) red[wid] = m;
  __syncthreads();
  m = fmaxf(fmaxf(red[0], red[1]), fmaxf(red[2], red[3]));
  float ex = __expf(ev - m);
  float s = wred_sum(ex);
  if (!lane) red[4 + wid] = s;
  __syncthreads();
  s = red[4] + red[5] + red[6] + red[7];
  if (t < LL) w_s[t] = ex / s;
  __syncthreads();

  int f0 = f8 * 256 + lane * 4;
  float a0 = 0.f, a1 = 0.f, a2 = 0.f, a3 = 0.f;
  int l0 = wid * 49;
  const u8* ap = att8 + ((size_t)(b * LL + l0)) * FF + f0;
#pragma unroll 7
  for (int l = 0; l < 49; ++l) {
    float wv = w_s[l0 + l];
    uint32_t pv = *reinterpret_cast<const uint32_t*>(ap);
    ap += FF;
    a0 += wv * __builtin_amdgcn_cvt_f32_fp8(pv, 0);
    a1 += wv * __builtin_amdgcn_cvt_f32_fp8(pv, 1);
    a2 += wv * __builtin_amdgcn_cvt_f32_fp8(pv, 2);
    a3 += wv * __builtin_amdgcn_cvt_f32_fp8(pv, 3);
  }
  *reinterpret_cast<float4*>(&part[wid][lane * 4]) = make_float4(a0, a1, a2, a3);
  __syncthreads();
  float v = part[0][t] + part[1][t] + part[2][t] + part[3][t];
  xatt[(size_t)b * FF + f8 * 256 + t] = f2bf(v);
}

// gates+LSTM: 128 blocks; XCD-dedup remap (R15-proven).
__global__ __launch_bounds__(256) void k_gatelstm(const u16* __restrict__ Xemb, const u16* __restrict__ xatt,
                                                  const u16* __restrict__ hb_in, const u16* __restrict__ Wc,
                                                  float* __restrict__ c, u16* __restrict__ hb_out, int tstep) {
  __shared__ float sm[4][4][16][16];
  int d = blockIdx.x;
  int bid = (d & 7) * 16 + (d >> 3);     // bijective: XCD x hosts jt in [x*4, x*4+4)
  int jt = bid >> 2, mq = bid & 3;
  int m0 = mq * 16;
  int lane = threadIdx.x & 63, kq = threadIdx.x >> 6;
  int ar = lane & 15, ak8 = (lane >> 4) * 8;
  int m = m0 + ar;
  int wn = jt * 16 + ar;
  f32x4 zero = {0.f, 0.f, 0.f, 0.f};
  f32x4 acc[4] = {zero, zero, zero, zero};
  const u16* xr0 = Xemb + ((size_t)tstep * BB + m) * HH;
  const u16* xr1 = xatt + (size_t)m * FF;
  const u16* xr2 = hb_in + (size_t)m * HH;

#pragma unroll 4
  for (int kk = 0; kk < 24; ++kk) {
    int k = kq * 768 + kk * 32 + ak8;
    short8 a;
    if (k < 512)       a = ldbf(xr0 + k);
    else if (k < 2560) a = ldbf(xr1 + (k - 512));
    else               a = ldbf(xr2 + (k - 2560));
    short8 bv[4];
#pragma unroll
    for (int g = 0; g < 4; ++g)
      bv[g] = ldbf(Wc + (size_t)(g * 512 + wn) * KXX + k);
#pragma unroll
    for (int g = 0; g < 4; ++g) acc[g] = mfma16(a, bv[g], acc[g]);
  }
#pragma unroll
  for (int g = 0; g < 4; ++g)
#pragma unroll
    for (int q = 0; q < 4; ++q)
      sm[kq][g][(lane >> 4) * 4 + q][ar] = acc[g][q];
  __syncthreads();
  int r = threadIdx.x >> 4, cc = threadIdx.x & 15;
  float gi = sm[0][0][r][cc] + sm[1][0][r][cc] + sm[2][0][r][cc] + sm[3][0][r][cc];
  float gf = sm[0][1][r][cc] + sm[1][1][r][cc] + sm[2][1][r][cc] + sm[3][1][r][cc];
  float gg = sm[0][2][r][cc] + sm[1][2][r][cc] + sm[2][2][r][cc] + sm[3][2][r][cc];
  float go = sm[0][3][r][cc] + sm[1][3][r][cc] + sm[2][3][r][cc] + sm[3][3][r][cc];
  int idx = (m0 + r) * HH + jt * 16 + cc;
  float cn = fast_sig(gf) * c[idx] + fast_sig(gi) * fast_tanh(gg);
  float hn = fast_sig(go) * fast_tanh(cn);
  c[idx] = cn;
  hb_out[idx] = f2bf(hn);
}

// ---------------- deferred logits (writes straight into d_out; proven) ----------------
__global__ __launch_bounds__(256) void k_logall(const u16* __restrict__ XhL, const u16* __restrict__ lWb,
                                                const float* __restrict__ lb, float* __restrict__ out) {
  __shared__ __align__(16) u16 As[128][32];
  __shared__ __align__(16) u16 Bs[128][32];
  int d = blockIdx.x;
  int mb = d & 7, nb = d >> 3;
  int m0 = mb * 128, n0 = nb * 128;
  int tid = threadIdx.x;
  int wid = tid >> 6, lane = tid & 63;
  int wr = wid >> 1, wc = wid & 1;
  int ar = lane & 15, ak = (lane >> 4) * 8;
  int rt = tid >> 1, st = tid & 1;
  const u16* agp = XhL + (size_t)(m0 + rt) * HH + st * 16;
  const u16* bgp = lWb + (size_t)(n0 + rt) * HH + st * 16;

  f32x4 zero = {0.f, 0.f, 0.f, 0.f};
  f32x4 acc[4][4];
#pragma unroll
  for (int i = 0; i < 4; ++i)
#pragma unroll
    for (int j = 0; j < 4; ++j) acc[i][j] = zero;

  for (int ks = 0; ks < 16; ++ks) {
    int k0 = ks * 32;
    short8 a0 = ldbf(agp + k0);
    short8 a1 = ldbf(agp + k0 + 8);
    short8 b0 = ldbf(bgp + k0);
    short8 b1 = ldbf(bgp + k0 + 8);
    __syncthreads();
    *reinterpret_cast<short8*>(&As[rt][st * 16]) = a0;
    *reinterpret_cast<short8*>(&As[rt][st * 16 + 8]) = a1;
    *reinterpret_cast<short8*>(&Bs[rt][st * 16]) = b0;
    *reinterpret_cast<short8*>(&Bs[rt][st * 16 + 8]) = b1;
    __syncthreads();
    short8 af[4], bfr[4];
#pragma unroll
    for (int i = 0; i < 4; ++i)
      af[i] = *reinterpret_cast<const short8*>(&As[wr * 64 + i * 16 + ar][ak]);
#pragma unroll
    for (int j = 0; j < 4; ++j)
      bfr[j] = *reinterpret_cast<const short8*>(&Bs[wc * 64 + j * 16 + ar][ak]);
#pragma unroll
    for (int i = 0; i < 4; ++i)
#pragma unroll
      for (int j = 0; j < 4; ++j)
        acc[i][j] = mfma16(af[i], bfr[j], acc[i][j]);
  }
#pragma unroll
  for (int j = 0; j < 4; ++j) {
    int col = n0 + wc * 64 + j * 16 + ar;
    if (col >= VV) continue;
    float bias = lb[col];
#pragma unroll
    for (int i = 0; i < 4; ++i)
#pragma unroll
      for (int q = 0; q < 4; ++q) {
        int row = m0 + wr * 64 + i * 16 + (lane >> 4) * 4 + q;
        int bb = row & 63, ts = row >> 6;
        out[((size_t)(bb * TT + ts)) * VV + col] = acc[i][j][q] + bias;
      }
  }
}

// in-place log-softmax on all 1024 out rows (proven)
__global__ __launch_bounds__(256) void k_lsmall(float* __restrict__ out) {
  __shared__ float red[8];
  float* row = out + (size_t)blockIdx.x * VV;
  float4* row4 = reinterpret_cast<float4*>(row);
  int t = threadIdx.x, wid = t >> 6, lane = t & 63;
  float4 v[10];
  float m = -1e30f;
#pragma unroll
  for (int p = 0; p < 10; ++p) {
    int i4 = p * 256 + t;
    if (i4 < VV / 4) {
      v[p] = row4[i4];
      m = fmaxf(m, fmaxf(fmaxf(v[p].x, v[p].y), fmaxf(v[p].z, v[p].w)));
    } else {
      v[p] = make_float4(-1e30f, -1e30f, -1e30f, -1e30f);
    }
  }
  m = wred_max(m);
  if (!lane) red[wid] = m;
  __syncthreads();
  m = fmaxf(fmaxf(red[0], red[1]), fmaxf(red[2], red[3]));
  float s = 0.f;
#pragma unroll
  for (int p = 0; p < 10; ++p)
    s += __expf(v[p].x - m) + __expf(v[p].y - m) + __expf(v[p].z - m) + __expf(v[p].w - m);
  s = wred_sum(s);
  if (!lane) red[4 + wid] = s;
  __syncthreads();
  s = red[4] + red[5] + red[6] + red[7];
  float lse = m + __logf(s);
#pragma unroll
  for (int p = 0; p < 10; ++p) {
    int i4 = p * 256 + t;
    if (i4 < VV / 4)
      row4[i4] = make_float4(v[p].x - lse, v[p].y - lse, v[p].z - lse, v[p].w - lse);
  }
}

// ---------------- host ----------------
extern "C" void kernel_launch(void* const* d_in, const int* in_sizes, int n_in,
                              void* d_out, int out_size, void* d_ws, size_t ws_size,
                              hipStream_t stream) {
  const float* fc      = (const float*)d_in[0];
  const float* attf    = (const float*)d_in[1];
  const int*   seq     = (const int*)d_in[2];
  const float* lin_W   = (const float*)d_in[3];
  const float* lin_b   = (const float*)d_in[4];
  const float* emb     = (const float*)d_in[5];
  const float* Wih     = (const float*)d_in[6];
  const float* Whh     = (const float*)d_in[7];
  const float* ctx_W   = (const float*)d_in[8];
  const float* ctx_b   = (const float*)d_in[9];
  const float* h2a_W   = (const float*)d_in[10];
  const float* h2a_b   = (const float*)d_in[11];
  const float* alpha_W = (const float*)d_in[12];
  const float* alpha_b = (const float*)d_in[13];
  const float* logit_W = (const float*)d_in[14];
  const float* logit_b = (const float*)d_in[15];
  float* out = (float*)d_out;

  char* base = (char*)d_ws;
  size_t off = 0;
  auto alloc = [&](size_t bytes) -> char* {
    off = (off + 255) & ~(size_t)255;
    char* p = base + off;
    off += bytes;
    return p;
  };
  // footprint ~61 MiB (well under proven ~117 MiB)
  u8*    p_att8 = (u8*)alloc((size_t)MM * HH);
  u8*    ctxW8  = (u8*)alloc((size_t)HH * FF);
  u16*   linWb  = (u16*)alloc((size_t)HH * FF * 2);
  u16*   fcb    = (u16*)alloc((size_t)BB * FF * 2);
  u16*   h2aWb  = (u16*)alloc((size_t)HH * HH * 2);
  u16*   Xemb   = (u16*)alloc((size_t)TT * BB * HH * 2);
  float* c      = (float*)alloc((size_t)BB * HH * 4);
  u16*   Xh     = (u16*)alloc((size_t)(TT + 1) * BB * HH * 2);   // slice 0 = h0
  u16*   xatt   = (u16*)alloc((size_t)BB * FF * 2);
  float* eb     = (float*)alloc((size_t)BB * 256 * 4);
  float* ah     = (float*)alloc((size_t)BB * HH * 4);
  u16*   Wc     = (u16*)alloc((size_t)2048 * KXX * 2);
  u16*   lWb    = (u16*)alloc((size_t)NPAD * HH * 2);   // pad rows: finite poison, never stored
  u8*    att8   = (u8*)alloc((size_t)MM * FF);
  (void)ws_size;

  k_setup<<<38920, 256, 0, stream>>>(ctx_W, ctxW8, lin_W, linWb, h2a_W, h2aWb, logit_W, lWb,
                                     fc, fcb, attf, att8, Wih, Whh, Wc, emb, seq, Xemb);
  // p_att GEMM (fp8) + h0 rider
  k_patt<<<424, 512, 0, stream>>>(att8, ctxW8, ctx_b, p_att8, fcb, linWb, lin_b, Xh, c);

  // prologue: ah(0), e(0)
  k_atth<<<32, 256, 0, stream>>>(Xh, h2aWb, h2a_b, ah);
  k_e<<<MM / 4, 256, 0, stream>>>(p_att8, ah, alpha_W, alpha_b, eb);

  for (int t = 0; t < TT; ++t) {
    u16* ht  = Xh + (size_t)t * BB * HH;
    u16* htn = Xh + (size_t)(t + 1) * BB * HH;
    k_attR<<<512, 256, 0, stream>>>(eb, att8, xatt);
    k_gatelstm<<<128, 256, 0, stream>>>(Xemb, xatt, ht, Wc, c, htn, t);
    if (t < TT - 1) {
      k_atth<<<32, 256, 0, stream>>>(htn, h2aWb, h2a_b, ah);
      k_e<<<MM / 4, 256, 0, stream>>>(p_att8, ah, alpha_W, alpha_b, eb);
    }
  }
  k_logall<<<600, 256, 0, stream>>>(Xh + (size_t)BB * HH, lWb, logit_b, out);
  k_lsmall<<<TT * BB, 256, 0, stream>>>(out);
}